// Round 15
// baseline (191.183 us; speedup 1.0000x reference)
//
#include <hip/hip_runtime.h>
#include <stdint.h>

typedef __bf16 bf16x8 __attribute__((ext_vector_type(8)));
typedef __bf16 bf16x4v __attribute__((ext_vector_type(4)));
typedef float f32x4 __attribute__((ext_vector_type(4)));
typedef float f32x2 __attribute__((ext_vector_type(2)));
typedef unsigned short u16x4 __attribute__((ext_vector_type(4)));
typedef unsigned short u16x8 __attribute__((ext_vector_type(8)));

#define NTOK 20000
#define NTP  20480
#define HIW  256
#define HD   2048
#define LDKP 66
#define LDS2 72
#define TSZ  16384   // shorts per kT/vT tile: 256 cols x 64 toks

static __device__ __forceinline__ float bf2f(unsigned short h) {
  union { unsigned u; float f; } c; c.u = ((unsigned)h) << 16;
  return c.f;
}
static __device__ __forceinline__ unsigned short fbits(float x) {
  __bf16 h = (__bf16)x;
  return __builtin_bit_cast(unsigned short, h);
}

#define WRED(x) { x += __shfl_xor(x,32); x += __shfl_xor(x,16); x += __shfl_xor(x,8); \
                  x += __shfl_xor(x,4);  x += __shfl_xor(x,2);  x += __shfl_xor(x,1); }

// Bt2 layout: (col,kk) -> addr = (((col>>4)*8 + (kk>>5))*64 + ((kk>>3)&3)*16 + (col&15))*8 + (kk&7)
// kT/vT layout: tile-major [tile][col][64]

// ===== k_front (256 thr): [0,640) k_tc | [640,768) k_pc split-K | 768 lambda | 769 zero-S =====
__global__ __launch_bounds__(256) void k_front(
    const float* __restrict__ kk, const float* __restrict__ vv,
    const float* __restrict__ Wq1, const float* __restrict__ Wk1,
    const float* __restrict__ Wq2, const float* __restrict__ Wk2,
    const float* __restrict__ lq1, const float* __restrict__ lk1,
    const float* __restrict__ lq2, const float* __restrict__ lk2,
    const float* __restrict__ bq1, const float* __restrict__ bk1,
    const float* __restrict__ bq2, const float* __restrict__ bk2,
    const int* __restrict__ layer,
    unsigned short* __restrict__ kT, unsigned short* __restrict__ vT,
    float* __restrict__ skp, float* __restrict__ svp,
    unsigned short* __restrict__ Pc_part, float* __restrict__ scal,
    float* __restrict__ S) {
  __shared__ float SMEM[64][260];   // 66560 B
  const int b = blockIdx.x, t = threadIdx.x;

  if (b < 640) {
    const int tile = b >> 1, m = b & 1;
    const float* src = m ? vv : kk;
    unsigned short* dstT = m ? vT : kT;
    float* sump = m ? svp : skp;
    #pragma unroll
    for (int i = 0; i < 16; ++i) {
      int ch = i * 256 + t;
      int row = ch >> 6, c4 = (ch & 63) * 4;
      int gtok = tile * 64 + row;
      f32x4 val = {0.f, 0.f, 0.f, 0.f};
      if (gtok < NTOK) val = *(const f32x4*)&src[(size_t)gtok * HIW + c4];
      *(f32x4*)&SMEM[row][c4] = val;
    }
    __syncthreads();
    float sum = 0.f;
    unsigned short cv[64];
    #pragma unroll
    for (int tok = 0; tok < 64; ++tok) {
      float x = SMEM[tok][t];
      sum += x;
      cv[tok] = fbits(x);
    }
    sump[tile * 256 + t] = sum;
    size_t base = (size_t)tile * TSZ + (size_t)t * 64;
    #pragma unroll
    for (int s = 0; s < 8; ++s)
      *(u16x8*)&dstT[base + s * 8] = *(const u16x8*)&cv[s * 8];
  } else if (b < 768) {
    // ---- Pc_part[pair*16+z] = Wa Wb^T K-slice (bf16 partials) ----
    unsigned short* Ak = (unsigned short*)SMEM;
    unsigned short* Bk = Ak + 128 * LDKP;
    const int idx = b - 640;
    const int pair = idx >> 6, rem = idx & 63;
    const int z = rem & 15, by = (rem >> 4) & 1, bx = (rem >> 5) & 1;
    const int i0 = bx * 128, j0 = by * 128;
    const int lane = t & 63, wave = t >> 6;
    const int wr = (wave >> 1) * 64, wc = (wave & 1) * 64;
    const int r15 = lane & 15, kg = (lane >> 4) * 8;
    const float* Wa = pair ? Wq2 : Wq1;
    const float* Wb = pair ? Wk2 : Wk1;
    f32x4 acc[4][4];
    #pragma unroll
    for (int m = 0; m < 4; ++m)
      #pragma unroll
      for (int n = 0; n < 4; ++n) acc[m][n] = (f32x4){0.f, 0.f, 0.f, 0.f};
    const int srow = t >> 1, sh = (t & 1) * 32;
    for (int kt = 0; kt < 2; ++kt) {
      const int kb = z * 128 + kt * 64 + sh;
      __syncthreads();
      #pragma unroll
      for (int c = 0; c < 8; ++c) {
        f32x4 a = *(const f32x4*)&Wa[(size_t)(i0 + srow) * HD + kb + c * 4];
        f32x4 bb = *(const f32x4*)&Wb[(size_t)(j0 + srow) * HD + kb + c * 4];
        bf16x4v oa, ob;
        #pragma unroll
        for (int u = 0; u < 4; ++u) { oa[u] = (__bf16)a[u]; ob[u] = (__bf16)bb[u]; }
        *(bf16x4v*)&Ak[srow * LDKP + sh + c * 4] = oa;
        *(bf16x4v*)&Bk[srow * LDKP + sh + c * 4] = ob;
      }
      __syncthreads();
      #pragma unroll
      for (int ks = 0; ks < 2; ++ks) {
        const int ko = ks * 32 + kg;
        bf16x8 ah[4], bh[4];
        #pragma unroll
        for (int m = 0; m < 4; ++m)
          ah[m] = *(const bf16x8*)&Ak[(wr + m * 16 + r15) * LDKP + ko];
        #pragma unroll
        for (int n = 0; n < 4; ++n)
          bh[n] = *(const bf16x8*)&Bk[(wc + n * 16 + r15) * LDKP + ko];
        #pragma unroll
        for (int m = 0; m < 4; ++m)
          #pragma unroll
          for (int n = 0; n < 4; ++n)
            acc[m][n] = __builtin_amdgcn_mfma_f32_16x16x32_bf16(ah[m], bh[n], acc[m][n], 0, 0, 0);
      }
    }
    const int rg = (lane >> 4) * 4;
    unsigned short* Pp = Pc_part + (size_t)(pair * 16 + z) * 65536;
    #pragma unroll
    for (int m = 0; m < 4; ++m)
      #pragma unroll
      for (int n = 0; n < 4; ++n)
        #pragma unroll
        for (int r = 0; r < 4; ++r)
          Pp[(i0 + wr + m * 16 + rg + r) * 256 + (j0 + wc + n * 16 + r15)] = fbits(acc[m][n][r]);
  } else if (b == 768) {
    float* red = (float*)SMEM;
    float p1 = lq1[t] * lk1[t], p2 = lq2[t] * lk2[t];
    float d1 = 0.f, d2 = 0.f;
    #pragma unroll
    for (int u = 0; u < 8; ++u) {
      d1 += bq1[t * 8 + u] * bk1[t * 8 + u];
      d2 += bq2[t * 8 + u] * bk2[t * 8 + u];
    }
    WRED(p1); WRED(p2); WRED(d1); WRED(d2);
    int w = t >> 6;
    if ((t & 63) == 0) { red[w] = p1; red[4 + w] = p2; red[8 + w] = d1; red[12 + w] = d2; }
    __syncthreads();
    if (t == 0) {
      float s1 = red[0] + red[1] + red[2] + red[3];
      float s2 = red[4] + red[5] + red[6] + red[7];
      float dd1 = red[8] + red[9] + red[10] + red[11];
      float dd2 = red[12] + red[13] + red[14] + red[15];
      float li = 0.8f - 0.6f * expf(-0.3f * (float)layer[0]);
      float lam = expf(s1) - expf(s2) + li;
      scal[0] = lam; scal[1] = -lam; scal[2] = 1.0f - li; scal[3] = li;
      scal[4] = dd1 - lam * dd2;
    }
  } else {
    const f32x4 z4 = {0.f, 0.f, 0.f, 0.f};
    #pragma unroll
    for (int i = 0; i < 64; ++i)
      *(f32x4*)&S[i * 1024 + t * 4] = z4;
  }
}

// ============ k_mid (512 thr): [0,640) S-GEMM z=160 (atomic) | [640,672) Pc-red |
//              [672,674) colsum-red | [674,706) gc/uc ============
__global__ __launch_bounds__(512) void k_mid(
    const unsigned short* __restrict__ kT, const unsigned short* __restrict__ vT,
    float* __restrict__ S, const unsigned short* __restrict__ Pc_part,
    const float* __restrict__ skp, const float* __restrict__ svp,
    float* __restrict__ Pc, float* __restrict__ sk, float* __restrict__ sv,
    const float* __restrict__ Wk1, const float* __restrict__ Wk2,
    const float* __restrict__ Wq1, const float* __restrict__ Wq2,
    const float* __restrict__ bq1, const float* __restrict__ bq2,
    const float* __restrict__ bk1, const float* __restrict__ bk2,
    const float* __restrict__ scal, float* __restrict__ gc, float* __restrict__ uc) {
  __shared__ unsigned short SB[2 * 2 * 128 * LDS2];
  const int b = blockIdx.x, t = threadIdx.x;

  if (b < 640) {
    const int z = b % 160, quad = b / 160;
    const int bx = quad >> 1, by = quad & 1;
    const int i0 = bx * 128, j0 = by * 128;
    const int lane = t & 63, wave = t >> 6;
    const int wr = (wave >> 1) * 32, wc = (wave & 1) * 64;
    const int r15 = lane & 15, kg = (lane >> 4) * 8;
    const int m = t >> 8;
    const int local = t & 255;
    const int row2 = local >> 1;
    const int koff = (local & 1) * 32;
    const unsigned short* srcT = m ? vT : kT;
    const size_t tbase = (size_t)(2 * z) * TSZ + (size_t)((m ? j0 : i0) + row2) * 64 + koff;
    const int lds_off = m * 128 * LDS2 + row2 * LDS2 + koff;

    f32x4 acc[2][4];
    #pragma unroll
    for (int mm = 0; mm < 2; ++mm)
      #pragma unroll
      for (int n = 0; n < 4; ++n) acc[mm][n] = (f32x4){0.f, 0.f, 0.f, 0.f};
    u16x8 rA[4], rB[4];

#define LOADT(R, KT)                                                          \
    { _Pragma("unroll")                                                       \
      for (int c = 0; c < 4; ++c)                                             \
        R[c] = *(const u16x8*)&srcT[tbase + (size_t)(KT) * TSZ + c * 8]; }
#define WRITET(BUF, R)                                                        \
    { unsigned short* d = &SB[(BUF) * 2 * 128 * LDS2 + lds_off];              \
      _Pragma("unroll")                                                       \
      for (int c = 0; c < 4; ++c) *(u16x8*)&d[c * 8] = R[c]; }
#define MFMAK(BUF)                                                            \
    { const unsigned short* Ab = &SB[(BUF) * 2 * 128 * LDS2];                 \
      const unsigned short* Bb = Ab + 128 * LDS2;                             \
      __builtin_amdgcn_s_setprio(1);                                          \
      _Pragma("unroll")                                                       \
      for (int ks = 0; ks < 2; ++ks) {                                        \
        const int ko = ks * 32 + kg;                                          \
        bf16x8 ah[2], bh[4];                                                  \
        _Pragma("unroll")                                                     \
        for (int mm = 0; mm < 2; ++mm)                                        \
          ah[mm] = *(const bf16x8*)&Ab[(wr + mm * 16 + r15) * LDS2 + ko];     \
        _Pragma("unroll")                                                     \
        for (int n = 0; n < 4; ++n)                                           \
          bh[n] = *(const bf16x8*)&Bb[(wc + n * 16 + r15) * LDS2 + ko];       \
        _Pragma("unroll")                                                     \
        for (int mm = 0; mm < 2; ++mm)                                        \
          _Pragma("unroll")                                                   \
          for (int n = 0; n < 4; ++n)                                         \
            acc[mm][n] = __builtin_amdgcn_mfma_f32_16x16x32_bf16(             \
                ah[mm], bh[n], acc[mm][n], 0, 0, 0);                          \
      }                                                                       \
      __builtin_amdgcn_s_setprio(0); }

    LOADT(rA, 0)
    WRITET(0, rA)
    LOADT(rB, 1)
    asm volatile("s_waitcnt lgkmcnt(0)" ::: "memory");
    __builtin_amdgcn_s_barrier();
    MFMAK(0)
    WRITET(1, rB)
    asm volatile("s_waitcnt lgkmcnt(0)" ::: "memory");
    __builtin_amdgcn_s_barrier();
    MFMAK(1)
#undef LOADT
#undef WRITET
#undef MFMAK
    const int rg = (lane >> 4) * 4;
    #pragma unroll
    for (int mm = 0; mm < 2; ++mm)
      #pragma unroll
      for (int n = 0; n < 4; ++n)
        #pragma unroll
        for (int r = 0; r < 4; ++r)
          atomicAdd(&S[(i0 + wr + mm * 16 + rg + r) * 256 + (j0 + wc + n * 16 + r15)],
                    acc[mm][n][r]);
  } else if (b < 672) {
    if (t < 256) {
      size_t idx = (size_t)(b - 640) * 2048 + t * 8;
      float s1[8] = {}, s2[8] = {};
      #pragma unroll 2
      for (int z = 0; z < 16; ++z) {
        u16x8 ha = *(const u16x8*)&Pc_part[(size_t)z * 65536 + idx];
        u16x8 hb = *(const u16x8*)&Pc_part[(size_t)(16 + z) * 65536 + idx];
        #pragma unroll
        for (int u = 0; u < 8; ++u) { s1[u] += bf2f(ha[u]); s2[u] += bf2f(hb[u]); }
      }
      float lam = scal[0];
      #pragma unroll
      for (int u = 0; u < 8; ++u) Pc[idx + u] = s1[u] - lam * s2[u];
    }
  } else if (b < 674) {
    if (t < 256) {
      const float* src = (b == 672) ? skp : svp;
      float s = 0.f;
      for (int z = 0; z < 320; ++z) s += src[z * 256 + t];
      if (b == 672) sk[t] = s; else sv[t] = s;
    }
  } else {
    if (t < 256) {
      int bb = b - 674, lane = t & 63, w = t >> 6;
      bool dogc = bb < 16;
      const float* A1 = dogc ? Wk1 : Wq1;
      const float* A2 = dogc ? Wk2 : Wq2;
      const float* x1 = dogc ? bq1 : bk1;
      const float* x2 = dogc ? bq2 : bk2;
      float* outv = dogc ? gc : uc;
      float lam = scal[0];
      int rb = (bb & 15) * 16 + w * 4;
      for (int q2 = 0; q2 < 4; ++q2) {
        int row = rb + q2;
        float s1 = 0.f, s2 = 0.f;
        #pragma unroll
        for (int c = 0; c < 8; ++c) {
          int kk2 = c * 256 + lane * 4;
          f32x4 a1 = *(const f32x4*)&A1[(size_t)row * HD + kk2];
          f32x4 a2 = *(const f32x4*)&A2[(size_t)row * HD + kk2];
          f32x4 v1 = *(const f32x4*)&x1[kk2];
          f32x4 v2 = *(const f32x4*)&x2[kk2];
          #pragma unroll
          for (int u = 0; u < 4; ++u) { s1 += a1[u] * v1[u]; s2 += a2[u] * v2[u]; }
        }
        WRED(s1); WRED(s2);
        if (lane == 0) outv[row] = s1 - lam * s2;
      }
    }
  }
}

// Ac = Pc @ S ; tc = Pc @ sk ; rv = S^T gc ; alpha_c = gc . sk
__global__ __launch_bounds__(256) void k_ac(
    const float* __restrict__ Pc, const float* __restrict__ S,
    const float* __restrict__ gc, const float* __restrict__ sk,
    float* __restrict__ Ac, float* __restrict__ tc, float* __restrict__ rv,
    float* __restrict__ scal) {
  int b = blockIdx.x, t = threadIdx.x;
  if (b < 32) {
    __shared__ float Pt[32][68];
    __shared__ float St[64][68];
    int i0 = (b >> 2) * 32, j0 = (b & 3) * 64;
    int ti = t >> 5, tj = t & 31;
    float acc[4][2] = {};
    for (int kt = 0; kt < 256; kt += 64) {
      __syncthreads();
      {
        int rr = t >> 3, c8 = (t & 7) * 8;
        *(f32x4*)&Pt[rr][c8] = *(const f32x4*)&Pc[(i0 + rr) * 256 + kt + c8];
        *(f32x4*)&Pt[rr][c8 + 4] = *(const f32x4*)&Pc[(i0 + rr) * 256 + kt + c8 + 4];
      }
      {
        int rr = t >> 2, c16 = (t & 3) * 16;
        #pragma unroll
        for (int c = 0; c < 4; ++c)
          *(f32x4*)&St[rr][c16 + c * 4] = *(const f32x4*)&S[(kt + rr) * 256 + j0 + c16 + c * 4];
      }
      __syncthreads();
      #pragma unroll 8
      for (int k2 = 0; k2 < 64; ++k2) {
        float a[4];
        #pragma unroll
        for (int u = 0; u < 4; ++u) a[u] = Pt[ti * 4 + u][k2];
        f32x2 b2 = *(const f32x2*)&St[k2][tj * 2];
        #pragma unroll
        for (int u = 0; u < 4; ++u) { acc[u][0] += a[u] * b2[0]; acc[u][1] += a[u] * b2[1]; }
      }
    }
    #pragma unroll
    for (int u = 0; u < 4; ++u) {
      Ac[(i0 + ti * 4 + u) * 256 + j0 + tj * 2] = acc[u][0];
      Ac[(i0 + ti * 4 + u) * 256 + j0 + tj * 2 + 1] = acc[u][1];
    }
  } else if (b == 32) {
    int lane = t & 63, w = t >> 6;
    f32x4 sk4 = *(const f32x4*)&sk[lane * 4];
    for (int ii = 0; ii < 64; ++ii) {
      int i = w * 64 + ii;
      f32x4 p4 = *(const f32x4*)&Pc[i * 256 + lane * 4];
      float s = p4[0] * sk4[0] + p4[1] * sk4[1] + p4[2] * sk4[2] + p4[3] * sk4[3];
      WRED(s);
      if (lane == 0) tc[i] = s;
    }
  } else {
    float s0 = 0.f, s1 = 0.f, s2 = 0.f, s3 = 0.f;
    #pragma unroll 4
    for (int i = 0; i < 256; i += 4) {
      s0 += gc[i] * S[i * 256 + t];
      s1 += gc[i + 1] * S[(i + 1) * 256 + t];
      s2 += gc[i + 2] * S[(i + 2) * 256 + t];
      s3 += gc[i + 3] * S[(i + 3) * 256 + t];
    }
    rv[t] = (s0 + s1) + (s2 + s3);
    if (t < 64) {
      f32x4 g4 = *(const f32x4*)&gc[t * 4];
      f32x4 sk4 = *(const f32x4*)&sk[t * 4];
      float a = g4[0] * sk4[0] + g4[1] * sk4[1] + g4[2] * sk4[2] + g4[3] * sk4[3];
      WRED(a);
      if (t == 0) scal[5] = a;
    }
  }
}

// Gc = Ac @ Wv + tc bv^T + uc (w + N bv)^T ; computes w/cc in-block
__global__ __launch_bounds__(256) void k_gc(
    const float* __restrict__ Ac, const float* __restrict__ Wv,
    const float* __restrict__ tc, const float* __restrict__ uc,
    const float* __restrict__ sv, const float* __restrict__ rv,
    const float* __restrict__ bv, const float* __restrict__ scal,
    float* __restrict__ Gc, float* __restrict__ cc) {
  __shared__ float At[64][68];
  __shared__ float Bt[64][132];
  __shared__ float svr[256], rvr[256];
  int t = threadIdx.x;
  int i0 = blockIdx.x * 64, j0 = blockIdx.y * 128;
  int ti = t >> 5, tj = t & 31;
  svr[t] = sv[t]; rvr[t] = rv[t];
  float acc[8][4] = {};
  f32x4 swa = {0.f, 0.f, 0.f, 0.f}, sca = {0.f, 0.f, 0.f, 0.f};
  for (int kt = 0; kt < 256; kt += 64) {
    __syncthreads();
    {
      int rr = t >> 2, c16 = (t & 3) * 16;
      #pragma unroll
      for (int c = 0; c < 4; ++c)
        *(f32x4*)&At[rr][c16 + c * 4] = *(const f32x4*)&Ac[(i0 + rr) * 256 + kt + c16 + c * 4];
    }
    {
      int rr = t >> 2, c32 = (t & 3) * 32;
      #pragma unroll
      for (int c = 0; c < 8; ++c)
        *(f32x4*)&Bt[rr][c32 + c * 4] = *(const f32x4*)&Wv[(size_t)(kt + rr) * HD + j0 + c32 + c * 4];
    }
    __syncthreads();
    #pragma unroll 8
    for (int k2 = 0; k2 < 64; ++k2) {
      float a[8];
      #pragma unroll
      for (int u = 0; u < 8; ++u) a[u] = At[ti * 8 + u][k2];
      f32x4 b = *(const f32x4*)&Bt[k2][tj * 4];
      float svk = svr[kt + k2], rvk = rvr[kt + k2];
      swa += b * svk; sca += b * rvk;
      #pragma unroll
      for (int u = 0; u < 8; ++u)
        #pragma unroll
        for (int v = 0; v < 4; ++v) acc[u][v] += a[u] * b[v];
    }
  }
  int j = j0 + tj * 4;
  f32x4 bv4 = *(const f32x4*)&bv[j];
  f32x4 wnb;
  #pragma unroll
  for (int v = 0; v < 4; ++v) wnb[v] = swa[v] + 20000.0f * bv4[v];
  if (blockIdx.x == 0 && ti == 0) {
    float ac = scal[5], dc = scal[4];
    f32x4 ccv;
    #pragma unroll
    for (int v = 0; v < 4; ++v) ccv[v] = sca[v] + ac * bv4[v] + dc * wnb[v];
    *(f32x4*)&cc[j] = ccv;
  }
  #pragma unroll
  for (int u = 0; u < 8; ++u) {
    int i = i0 + ti * 8 + u;
    float tci = tc[i], uci = uc[i];
    f32x4 o;
    #pragma unroll
    for (int v = 0; v < 4; ++v)
      o[v] = acc[u][v] + tci * bv4[v] + uci * wnb[v];
    *(f32x4*)&Gc[(size_t)i * HD + j] = o;
  }
}

// merged: [0,17) scal2 | [17,81) M = Gc Gc^T 64x64 tiles | [81,225) Hc partials
__global__ __launch_bounds__(256) void k_post(
    const float* __restrict__ Gc, const float* __restrict__ cc,
    const float* __restrict__ Wo, const float* __restrict__ g,
    const float* __restrict__ lnb, const float* __restrict__ scal_c,
    unsigned short* __restrict__ Bt2, float* __restrict__ M_part,
    float* __restrict__ Hc_part, float* __restrict__ scal) {
  __shared__ float SMEM[8768];
  int b = blockIdx.x, t = threadIdx.x;
  if (b < 17) {
    int lane = t & 63, w = t >> 6;
    if (b < 16) {
      int rb = b * 16 + w * 4;
      for (int q2 = 0; q2 < 4; ++q2) {
        int row = rb + q2;
        float s1 = 0.f, s2 = 0.f;
        #pragma unroll
        for (int c = 0; c < 8; ++c) {
          int kk2 = c * 256 + lane * 4;
          f32x4 g4 = *(const f32x4*)&Gc[(size_t)row * HD + kk2];
          f32x4 c4v = *(const f32x4*)&cc[kk2];
          #pragma unroll
          for (int u = 0; u < 4; ++u) { s1 += g4[u]; s2 += g4[u] * c4v[u]; }
        }
        WRED(s1); WRED(s2);
        if (lane == 0) {
          int base = ((256 + (row >> 5)) * 64 + ((row >> 3) & 3) * 16) * 8 + (row & 7);
          Bt2[base] = fbits(s1 * (1.0f / 2048.0f));
          Bt2[base + 8] = fbits(s2);
        }
      }
    } else {
      float s1 = 0.f, s2 = 0.f;
      #pragma unroll
      for (int c = 0; c < 2; ++c) {
        f32x4 v = *(const f32x4*)&cc[t * 8 + c * 4];
        #pragma unroll
        for (int u = 0; u < 4; ++u) { s1 += v[u]; s2 += v[u] * v[u]; }
      }
      WRED(s1); WRED(s2);
      if ((t & 63) == 0) { SMEM[t >> 6] = s1; SMEM[4 + (t >> 6)] = s2; }
      __syncthreads();
      if (t == 0) {
        scal[6] = SMEM[4] + SMEM[5] + SMEM[6] + SMEM[7];
        scal[7] = (SMEM[0] + SMEM[1] + SMEM[2] + SMEM[3]) * (1.0f / 2048.0f);
      }
      for (int idx = t; idx < 14 * 256; idx += 256) {
        int ci = idx >> 8, kk2 = idx & 255;
        int col = 514 + ci;
        Bt2[((256 + (kk2 >> 5)) * 64 + ((kk2 >> 3) & 3) * 16 + (col & 15)) * 8 + (kk2 & 7)] = 0;
      }
    }
  } else if (b < 81) {
    float (*Gi)[68] = (float(*)[68])SMEM;
    float (*Gj)[69] = (float(*)[69])(SMEM + 64 * 68);
    int idx = b - 17;
    int bx = idx & 3, by = (idx >> 2) & 3, z = idx >> 4;
    int i0 = bx * 64, j0 = by * 64;
    int ti = t >> 5, tj = t & 31;
    float acc[8][2] = {};
    for (int kt = 0; kt < 512; kt += 64) {
      int kb = z * 512 + kt;
      __syncthreads();
      {
        int rr = t >> 2, c16 = (t & 3) * 16;
        #pragma unroll
        for (int c = 0; c < 4; ++c) {
          *(f32x4*)&Gi[rr][c16 + c * 4] = *(const f32x4*)&Gc[(size_t)(i0 + rr) * HD + kb + c16 + c * 4];
          *(f32x4*)&Gj[rr][c16 + c * 4] = *(const f32x4*)&Gc[(size_t)(j0 + rr) * HD + kb + c16 + c * 4];
        }
      }
      __syncthreads();
      #pragma unroll 8
      for (int k2 = 0; k2 < 64; ++k2) {
        float a[8];
        #pragma unroll
        for (int u = 0; u < 8; ++u) a[u] = Gi[ti * 8 + u][k2];
        float b0 = Gj[tj * 2][k2], b1 = Gj[tj * 2 + 1][k2];
        #pragma unroll
        for (int u = 0; u < 8; ++u) { acc[u][0] += a[u] * b0; acc[u][1] += a[u] * b1; }
      }
    }
    #pragma unroll
    for (int u = 0; u < 8; ++u) {
      M_part[(size_t)z * 65536 + (i0 + ti * 8 + u) * 256 + j0 + tj * 2] = acc[u][0];
      M_part[(size_t)z * 65536 + (i0 + ti * 8 + u) * 256 + j0 + tj * 2 + 1] = acc[u][1];
    }
  } else {
    float (*At)[68] = (float(*)[68])SMEM;
    float (*Bt)[68] = (float(*)[68])(SMEM + 32 * 68);
    int idx = b - 81;
    int bx = idx % 9, rem = idx / 9, by = rem & 3, z = rem >> 2;
    int i0 = bx * 32, j0 = by * 64;
    float s2 = scal_c[2];
    int ti = t >> 5, tj = t & 31;
    float acc[4][2] = {};
    for (int kt = 0; kt < 512; kt += 64) {
      int kb = z * 512 + kt;
      __syncthreads();
      {
        int rr = t >> 3, c8 = (t & 7) * 8, gi = i0 + rr;
        #pragma unroll
        for (int h = 0; h < 8; h += 4) {
          f32x4 g4 = *(const f32x4*)&g[kb + c8 + h];
          f32x4 a;
          if (gi < 256) {
            f32x4 gg = *(const f32x4*)&Gc[(size_t)gi * HD + kb + c8 + h];
            #pragma unroll
            for (int u = 0; u < 4; ++u) a[u] = gg[u] * g4[u];
          } else if (gi == 256) {
            a = g4;
          } else if (gi == 257) {
            f32x4 c4v = *(const f32x4*)&cc[kb + c8 + h];
            #pragma unroll
            for (int u = 0; u < 4; ++u) a[u] = c4v[u] * g4[u];
          } else if (gi == 258) {
            a = *(const f32x4*)&lnb[kb + c8 + h];
          } else {
            a = (f32x4){0.f, 0.f, 0.f, 0.f};
          }
          *(f32x4*)&At[rr][c8 + h] = a;
        }
      }
      {
        int rr = t >> 2, c16 = (t & 3) * 16;
        #pragma unroll
        for (int c = 0; c < 4; ++c) {
          f32x4 bb = *(const f32x4*)&Wo[(size_t)(kb + rr) * 256 + j0 + c16 + c * 4];
          #pragma unroll
          for (int u = 0; u < 4; ++u) bb[u] *= s2;
          *(f32x4*)&Bt[rr][c16 + c * 4] = bb;
        }
      }
      __syncthreads();
      #pragma unroll 8
      for (int k2 = 0; k2 < 64; ++k2) {
        float a[4];
        #pragma unroll
        for (int u = 0; u < 4; ++u) a[u] = At[ti * 4 + u][k2];
        f32x2 b2 = *(const f32x2*)&Bt[k2][tj * 2];
        #pragma unroll
        for (int u = 0; u < 4; ++u) { acc[u][0] += a[u] * b2[0]; acc[u][1] += a[u] * b2[1]; }
      }
    }
    #pragma unroll
    for (int u = 0; u < 4; ++u) {
      Hc_part[(size_t)z * 73728 + (i0 + ti * 4 + u) * 256 + j0 + tj * 2] = acc[u][0];
      Hc_part[(size_t)z * 73728 + (i0 + ti * 4 + u) * 256 + j0 + tj * 2 + 1] = acc[u][1];
    }
  }
}

// reduce M/Hc partials -> Bt2 (wave-contiguous bf16); vectors wbar/hc/bc
__global__ __launch_bounds__(256) void k_red2(
    const float* __restrict__ M_part, const float* __restrict__ Hc_part,
    const float* __restrict__ bo, unsigned short* __restrict__ Bt2,
    float* __restrict__ wbar, float* __restrict__ hcv, float* __restrict__ bcv) {
  int bi = blockIdx.x, z2 = blockIdx.y, t = threadIdx.x;
  if (z2 == 2) {
    if (bi != 0) return;
    float s0 = 0.f, s1 = 0.f, s2 = 0.f;
    #pragma unroll
    for (int z = 0; z < 4; ++z) {
      s0 += Hc_part[(size_t)z * 73728 + 256 * 256 + t];
      s1 += Hc_part[(size_t)z * 73728 + 257 * 256 + t];
      s2 += Hc_part[(size_t)z * 73728 + 258 * 256 + t];
    }
    wbar[t] = s0; hcv[t] = s1; bcv[t] = s2 + bo[t];
    return;
  }
  __shared__ unsigned short T[64][256];
  const float* src = z2 ? Hc_part : M_part;
  const size_t sp = z2 ? 73728 : 65536;
  const int base = z2 ? 256 : 0;
  for (int ii = 0; ii < 64; ++ii) {
    int i = bi * 64 + ii;
    float s = 0.f;
    #pragma unroll
    for (int z = 0; z < 4; ++z) s += src[z * sp + i * 256 + t];
    T[ii][t] = fbits(s);
  }
  __syncthreads();
  const int col = base + t;
  #pragma unroll
  for (int c = 0; c < 64; c += 8) {
    u16x8 o;
    #pragma unroll
    for (int u = 0; u < 8; ++u) o[u] = T[c + u][t];
    int kk0 = bi * 64 + c;
    int addr = (((col >> 4) * 8 + (kk0 >> 5)) * 64 + ((kk0 >> 3) & 3) * 16 + (col & 15)) * 8;
    *(u16x8*)&Bt2[addr] = o;
  }
}

// fused final (512 thr, 8 waves, 64 cols/wave): y|z|mu|m2 = q @ Bt2 + LN epilogue
__global__ __launch_bounds__(512) void k_out(
    const float* __restrict__ q, const unsigned short* __restrict__ Bt2,
    const float* __restrict__ hcv, const float* __restrict__ wbar,
    const float* __restrict__ bcv, const float* __restrict__ scal,
    float* __restrict__ out) {
  __shared__ unsigned short As[32 * 264];
  __shared__ unsigned short zbuf[32][264];
  __shared__ float sqp[4][32];
  __shared__ float muL[32], m2L[32];
  const int t = threadIdx.x, lane = t & 63, wave = t >> 6;
  const int row0 = blockIdx.x * 32;
  const int r15 = lane & 15, kg = lane >> 4;
  {
    #pragma unroll
    for (int i = 0; i < 4; ++i) {
      int ch = i * 512 + t;
      int row = ch >> 6, c4 = (ch & 63) * 4;
      f32x4 v = *(const f32x4*)&q[(size_t)(row0 + row) * HIW + c4];
      bf16x4v o;
      #pragma unroll
      for (int u = 0; u < 4; ++u) o[u] = (__bf16)v[u];
      *(bf16x4v*)&As[row * 264 + c4] = o;
    }
  }
  __syncthreads();
  const bool isM = wave < 4;
  const int wcol = isM ? wave * 64 : 256 + (wave - 4) * 64;
  const int grp0 = wcol >> 4;
  f32x4 acc[2][5];
  #pragma unroll
  for (int m = 0; m < 2; ++m)
    #pragma unroll
    for (int n = 0; n < 5; ++n) acc[m][n] = (f32x4){0.f, 0.f, 0.f, 0.f};
  __builtin_amdgcn_s_setprio(1);
  #pragma unroll
  for (int ko = 0; ko < 8; ++ko) {
    bf16x8 af0 = *(const bf16x8*)&As[r15 * 264 + ko * 32 + kg * 8];
    bf16x8 af1 = *(const bf16x8*)&As[(16 + r15) * 264 + ko * 32 + kg * 8];
    #pragma unroll
    for (int ni = 0; ni < 5; ++ni) {
      if (ni == 4 && wave != 7) continue;
      const int grp = (ni == 4) ? 32 : grp0 + ni;
      bf16x8 bfr = *(const bf16x8*)&Bt2[(size_t)(grp * 8 + ko) * 512 + lane * 8];
      acc[0][ni] = __builtin_amdgcn_mfma_f32_16x16x32_bf16(af0, bfr, acc[0][ni], 0, 0, 0);
      acc[1][ni] = __builtin_amdgcn_mfma_f32_16x16x32_bf16(af1, bfr, acc[1][ni], 0, 0, 0);
    }
  }
  __builtin_amdgcn_s_setprio(0);
  if (isM) {
    #pragma unroll
    for (int m = 0; m < 2; ++m)
      #pragma unroll
      for (int r = 0; r < 4; ++r) {
        int rowl = m * 16 + kg * 4 + r;
        float p = 0.f;
        #pragma unroll
        for (int ni = 0; ni < 4; ++ni) {
          int col = wcol + ni * 16 + r15;
          p += acc[m][ni][r] * bf2f(As[rowl * 264 + col]);
        }
        p += __shfl_xor(p, 1); p += __shfl_xor(p, 2);
        p += __shfl_xor(p, 4); p += __shfl_xor(p, 8);
        if (r15 == 0) sqp[wave][rowl] = p;
      }
  } else {
    #pragma unroll
    for (int m = 0; m < 2; ++m)
      #pragma unroll
      for (int r = 0; r < 4; ++r) {
        int rowl = m * 16 + kg * 4 + r;
        #pragma unroll
        for (int ni = 0; ni < 4; ++ni)
          zbuf[rowl][(wcol - 256) + ni * 16 + r15] = fbits(acc[m][ni][r]);
      }
    if (wave == 7) {
      #pragma unroll
      for (int m = 0; m < 2; ++m)
        #pragma unroll
        for (int r = 0; r < 4; ++r) {
          int rowl = m * 16 + kg * 4 + r;
          if (r15 == 0) muL[rowl] = acc[m][4][r];
          if (r15 == 1) m2L[rowl] = acc[m][4][r];
        }
    }
  }
  __syncthreads();
  const float css = scal[6], cbar = scal[7];
  #pragma unroll
  for (int i = 0; i < 4; ++i) {
    const int row = i * 8 + wave;
    const int c4 = lane * 4;
    float mu = muL[row] + cbar;
    float ss = (sqp[0][row] + sqp[1][row]) + (sqp[2][row] + sqp[3][row]) +
               2.0f * m2L[row] + css;
    float var = ss * (1.0f / 2048.0f) - mu * mu;
    float rstd = rsqrtf(var + 1e-5f);
    u16x4 zh = *(const u16x4*)&zbuf[row][c4];
    f32x4 h4 = *(const f32x4*)&hcv[c4];
    f32x4 w4 = *(const f32x4*)&wbar[c4];
    f32x4 b4 = *(const f32x4*)&bcv[c4];
    f32x4 o;
    #pragma unroll
    for (int u = 0; u < 4; ++u)
      o[u] = rstd * (bf2f(zh[u]) + h4[u] - mu * w4[u]) + b4[u];
    *(f32x4*)&out[(size_t)(row0 + row) * HIW + c4] = o;
  }
}

extern "C" void kernel_launch(void* const* d_in, const int* in_sizes, int n_in,
                              void* d_out, int out_size, void* d_ws, size_t ws_size,
                              hipStream_t stream) {
  const float* q   = (const float*)d_in[0];
  const float* k   = (const float*)d_in[1];
  const float* v   = (const float*)d_in[2];
  const int* layer = (const int*)d_in[3];
  const float* Wq1 = (const float*)d_in[4];  const float* bq1 = (const float*)d_in[5];
  const float* Wk1 = (const float*)d_in[6];  const float* bk1 = (const float*)d_in[7];
  const float* Wq2 = (const float*)d_in[8];  const float* bq2 = (const float*)d_in[9];
  const float* Wk2 = (const float*)d_in[10]; const float* bk2 = (const float*)d_in[11];
  const float* Wv  = (const float*)d_in[12]; const float* bv  = (const float*)d_in[13];
  const float* lng = (const float*)d_in[14]; const float* lnb = (const float*)d_in[15];
  const float* Wo  = (const float*)d_in[16]; const float* bo  = (const float*)d_in[17];
  const float* lq1 = (const float*)d_in[18]; const float* lk1 = (const float*)d_in[19];
  const float* lq2 = (const float*)d_in[20]; const float* lk2 = (const float*)d_in[21];

  char* p = (char*)d_ws;
  unsigned short* kT = (unsigned short*)p;
  float* M_part  = (float*)p;
  float* Hc_part = (float*)(p + 1048576);
  unsigned short* Bt2 = (unsigned short*)(p + 1048576 + 1179648);
  p += (size_t)256 * NTP * 2;
  unsigned short* vT = (unsigned short*)p;
  float* Gc = (float*)p;
  p += (size_t)256 * NTP * 2;
  float* skp = (float*)p;     p += (size_t)320 * 256 * 4;
  float* svp = (float*)p;     p += (size_t)320 * 256 * 4;
  unsigned short* Pc_part = (unsigned short*)p; p += (size_t)32 * 65536 * 2;
  float* S  = (float*)p;      p += 65536 * 4;
  float* Pc = (float*)p;      p += 65536 * 4;
  float* sk = (float*)p;      p += 1024;
  float* sv = (float*)p;      p += 1024;
  float* gc = (float*)p;      p += 1024;
  float* uc = (float*)p;      p += 1024;
  float* tc = (float*)p;      p += 1024;
  float* rv = (float*)p;      p += 1024;
  float* cc = (float*)p;      p += 2048 * 4;
  float* Ac = (float*)p;      p += 65536 * 4;
  float* wbar = (float*)p;    p += 1024;
  float* hcv  = (float*)p;    p += 1024;
  float* bcv  = (float*)p;    p += 1024;
  float* scal = (float*)p;    p += 256;

  const dim3 b256(256);
  k_front<<<dim3(770), b256, 0, stream>>>(k, v, Wq1, Wk1, Wq2, Wk2,
      lq1, lk1, lq2, lk2, bq1, bk1, bq2, bk2, layer, kT, vT, skp, svp, Pc_part, scal, S);
  k_mid<<<dim3(706), dim3(512), 0, stream>>>(kT, vT, S, Pc_part, skp, svp, Pc, sk, sv,
      Wk1, Wk2, Wq1, Wq2, bq1, bq2, bk1, bk2, scal, gc, uc);
  k_ac<<<dim3(34), b256, 0, stream>>>(Pc, S, gc, sk, Ac, tc, rv, scal);
  k_gc<<<dim3(4, 16), b256, 0, stream>>>(Ac, Wv, tc, uc, sv, rv, bv, scal, Gc, cc);
  k_post<<<dim3(225), b256, 0, stream>>>(Gc, cc, Wo, lng, lnb, scal, Bt2, M_part, Hc_part, scal);
  k_red2<<<dim3(4, 3), b256, 0, stream>>>(M_part, Hc_part, bo, Bt2, wbar, hcv, bcv);
  k_out<<<dim3(625), dim3(512), 0, stream>>>(q, Bt2, hcv, wbar, bcv, scal, (float*)d_out);
}

// Round 16
// 168.767 us; speedup vs baseline: 1.1328x; 1.1328x over previous
//
#include <hip/hip_runtime.h>
#include <stdint.h>

typedef __bf16 bf16x8 __attribute__((ext_vector_type(8)));
typedef __bf16 bf16x4v __attribute__((ext_vector_type(4)));
typedef float f32x4 __attribute__((ext_vector_type(4)));
typedef float f32x2 __attribute__((ext_vector_type(2)));
typedef unsigned short u16x4 __attribute__((ext_vector_type(4)));
typedef unsigned short u16x8 __attribute__((ext_vector_type(8)));

#define NTOK 20000
#define NTP  20480
#define HIW  256
#define HD   2048
#define LDKP 66
#define LDS2 72
#define TSZ  16384   // shorts per kT/vT tile: 256 cols x 64 toks

static __device__ __forceinline__ float bf2f(unsigned short h) {
  union { unsigned u; float f; } c; c.u = ((unsigned)h) << 16;
  return c.f;
}
static __device__ __forceinline__ unsigned short fbits(float x) {
  __bf16 h = (__bf16)x;
  return __builtin_bit_cast(unsigned short, h);
}

#define WRED(x) { x += __shfl_xor(x,32); x += __shfl_xor(x,16); x += __shfl_xor(x,8); \
                  x += __shfl_xor(x,4);  x += __shfl_xor(x,2);  x += __shfl_xor(x,1); }

// Bt2 layout: (col,kk) -> addr = (((col>>4)*8 + (kk>>5))*64 + ((kk>>3)&3)*16 + (col&15))*8 + (kk&7)
// kT/vT layout: tile-major [tile][col][64]

// ===== k_front (256 thr): [0,640) k_tc | [640,768) k_pc split-K | 768 lambda | 769 zero-S =====
__global__ __launch_bounds__(256) void k_front(
    const float* __restrict__ kk, const float* __restrict__ vv,
    const float* __restrict__ Wq1, const float* __restrict__ Wk1,
    const float* __restrict__ Wq2, const float* __restrict__ Wk2,
    const float* __restrict__ lq1, const float* __restrict__ lk1,
    const float* __restrict__ lq2, const float* __restrict__ lk2,
    const float* __restrict__ bq1, const float* __restrict__ bk1,
    const float* __restrict__ bq2, const float* __restrict__ bk2,
    const int* __restrict__ layer,
    unsigned short* __restrict__ kT, unsigned short* __restrict__ vT,
    float* __restrict__ skp, float* __restrict__ svp,
    unsigned short* __restrict__ Pc_part, float* __restrict__ scal,
    float* __restrict__ S) {
  __shared__ float SMEM[64][260];   // 66560 B
  const int b = blockIdx.x, t = threadIdx.x;

  if (b < 640) {
    const int tile = b >> 1, m = b & 1;
    const float* src = m ? vv : kk;
    unsigned short* dstT = m ? vT : kT;
    float* sump = m ? svp : skp;
    #pragma unroll
    for (int i = 0; i < 16; ++i) {
      int ch = i * 256 + t;
      int row = ch >> 6, c4 = (ch & 63) * 4;
      int gtok = tile * 64 + row;
      f32x4 val = {0.f, 0.f, 0.f, 0.f};
      if (gtok < NTOK) val = *(const f32x4*)&src[(size_t)gtok * HIW + c4];
      *(f32x4*)&SMEM[row][c4] = val;
    }
    __syncthreads();
    float sum = 0.f;
    unsigned short cv[64];
    #pragma unroll
    for (int tok = 0; tok < 64; ++tok) {
      float x = SMEM[tok][t];
      sum += x;
      cv[tok] = fbits(x);
    }
    sump[tile * 256 + t] = sum;
    size_t base = (size_t)tile * TSZ + (size_t)t * 64;
    #pragma unroll
    for (int s = 0; s < 8; ++s)
      *(u16x8*)&dstT[base + s * 8] = *(const u16x8*)&cv[s * 8];
  } else if (b < 768) {
    // ---- Pc_part[pair*16+z] = Wa Wb^T K-slice (bf16 partials) ----
    unsigned short* Ak = (unsigned short*)SMEM;
    unsigned short* Bk = Ak + 128 * LDKP;
    const int idx = b - 640;
    const int pair = idx >> 6, rem = idx & 63;
    const int z = rem & 15, by = (rem >> 4) & 1, bx = (rem >> 5) & 1;
    const int i0 = bx * 128, j0 = by * 128;
    const int lane = t & 63, wave = t >> 6;
    const int wr = (wave >> 1) * 64, wc = (wave & 1) * 64;
    const int r15 = lane & 15, kg = (lane >> 4) * 8;
    const float* Wa = pair ? Wq2 : Wq1;
    const float* Wb = pair ? Wk2 : Wk1;
    f32x4 acc[4][4];
    #pragma unroll
    for (int m = 0; m < 4; ++m)
      #pragma unroll
      for (int n = 0; n < 4; ++n) acc[m][n] = (f32x4){0.f, 0.f, 0.f, 0.f};
    const int srow = t >> 1, sh = (t & 1) * 32;
    for (int kt = 0; kt < 2; ++kt) {
      const int kb = z * 128 + kt * 64 + sh;
      __syncthreads();
      #pragma unroll
      for (int c = 0; c < 8; ++c) {
        f32x4 a = *(const f32x4*)&Wa[(size_t)(i0 + srow) * HD + kb + c * 4];
        f32x4 bb = *(const f32x4*)&Wb[(size_t)(j0 + srow) * HD + kb + c * 4];
        bf16x4v oa, ob;
        #pragma unroll
        for (int u = 0; u < 4; ++u) { oa[u] = (__bf16)a[u]; ob[u] = (__bf16)bb[u]; }
        *(bf16x4v*)&Ak[srow * LDKP + sh + c * 4] = oa;
        *(bf16x4v*)&Bk[srow * LDKP + sh + c * 4] = ob;
      }
      __syncthreads();
      #pragma unroll
      for (int ks = 0; ks < 2; ++ks) {
        const int ko = ks * 32 + kg;
        bf16x8 ah[4], bh[4];
        #pragma unroll
        for (int m = 0; m < 4; ++m)
          ah[m] = *(const bf16x8*)&Ak[(wr + m * 16 + r15) * LDKP + ko];
        #pragma unroll
        for (int n = 0; n < 4; ++n)
          bh[n] = *(const bf16x8*)&Bk[(wc + n * 16 + r15) * LDKP + ko];
        #pragma unroll
        for (int m = 0; m < 4; ++m)
          #pragma unroll
          for (int n = 0; n < 4; ++n)
            acc[m][n] = __builtin_amdgcn_mfma_f32_16x16x32_bf16(ah[m], bh[n], acc[m][n], 0, 0, 0);
      }
    }
    const int rg = (lane >> 4) * 4;
    unsigned short* Pp = Pc_part + (size_t)(pair * 16 + z) * 65536;
    #pragma unroll
    for (int m = 0; m < 4; ++m)
      #pragma unroll
      for (int n = 0; n < 4; ++n)
        #pragma unroll
        for (int r = 0; r < 4; ++r)
          Pp[(i0 + wr + m * 16 + rg + r) * 256 + (j0 + wc + n * 16 + r15)] = fbits(acc[m][n][r]);
  } else if (b == 768) {
    float* red = (float*)SMEM;
    float p1 = lq1[t] * lk1[t], p2 = lq2[t] * lk2[t];
    float d1 = 0.f, d2 = 0.f;
    #pragma unroll
    for (int u = 0; u < 8; ++u) {
      d1 += bq1[t * 8 + u] * bk1[t * 8 + u];
      d2 += bq2[t * 8 + u] * bk2[t * 8 + u];
    }
    WRED(p1); WRED(p2); WRED(d1); WRED(d2);
    int w = t >> 6;
    if ((t & 63) == 0) { red[w] = p1; red[4 + w] = p2; red[8 + w] = d1; red[12 + w] = d2; }
    __syncthreads();
    if (t == 0) {
      float s1 = red[0] + red[1] + red[2] + red[3];
      float s2 = red[4] + red[5] + red[6] + red[7];
      float dd1 = red[8] + red[9] + red[10] + red[11];
      float dd2 = red[12] + red[13] + red[14] + red[15];
      float li = 0.8f - 0.6f * expf(-0.3f * (float)layer[0]);
      float lam = expf(s1) - expf(s2) + li;
      scal[0] = lam; scal[1] = -lam; scal[2] = 1.0f - li; scal[3] = li;
      scal[4] = dd1 - lam * dd2;
    }
  } else {
    const f32x4 z4 = {0.f, 0.f, 0.f, 0.f};
    #pragma unroll
    for (int i = 0; i < 64; ++i)
      *(f32x4*)&S[i * 1024 + t * 4] = z4;
  }
}

// ============ k_mid (512 thr): [0,256) S-GEMM(atomic) | [256,288) Pc-red |
//              [288,290) colsum-red | [290,322) gc/uc ============
__global__ __launch_bounds__(512) void k_mid(
    const unsigned short* __restrict__ kT, const unsigned short* __restrict__ vT,
    float* __restrict__ S, const unsigned short* __restrict__ Pc_part,
    const float* __restrict__ skp, const float* __restrict__ svp,
    float* __restrict__ Pc, float* __restrict__ sk, float* __restrict__ sv,
    const float* __restrict__ Wk1, const float* __restrict__ Wk2,
    const float* __restrict__ Wq1, const float* __restrict__ Wq2,
    const float* __restrict__ bq1, const float* __restrict__ bq2,
    const float* __restrict__ bk1, const float* __restrict__ bk2,
    const float* __restrict__ scal, float* __restrict__ gc, float* __restrict__ uc) {
  __shared__ unsigned short SB[2 * 2 * 128 * LDS2];
  const int b = blockIdx.x, t = threadIdx.x;

  if (b < 256) {
    const int z = b & 63, by = (b >> 6) & 1, bx = (b >> 7) & 1;
    const int i0 = bx * 128, j0 = by * 128;
    const int lane = t & 63, wave = t >> 6;
    const int wr = (wave >> 1) * 32, wc = (wave & 1) * 64;
    const int r15 = lane & 15, kg = (lane >> 4) * 8;
    const int m = t >> 8;
    const int local = t & 255;
    const int row2 = local >> 1;
    const int koff = (local & 1) * 32;
    const unsigned short* srcT = m ? vT : kT;
    const size_t tbase = (size_t)(5 * z) * TSZ + (size_t)((m ? j0 : i0) + row2) * 64 + koff;
    const int lds_off = m * 128 * LDS2 + row2 * LDS2 + koff;

    f32x4 acc[2][4];
    #pragma unroll
    for (int mm = 0; mm < 2; ++mm)
      #pragma unroll
      for (int n = 0; n < 4; ++n) acc[mm][n] = (f32x4){0.f, 0.f, 0.f, 0.f};
    u16x8 rA[4], rB[4];

#define LOADT(R, KT)                                                          \
    { _Pragma("unroll")                                                       \
      for (int c = 0; c < 4; ++c)                                             \
        R[c] = *(const u16x8*)&srcT[tbase + (size_t)(KT) * TSZ + c * 8]; }
#define WRITET(BUF, R)                                                        \
    { unsigned short* d = &SB[(BUF) * 2 * 128 * LDS2 + lds_off];              \
      _Pragma("unroll")                                                       \
      for (int c = 0; c < 4; ++c) *(u16x8*)&d[c * 8] = R[c]; }

    LOADT(rA, 0)
    WRITET(0, rA)
    LOADT(rB, 1)
    asm volatile("s_waitcnt lgkmcnt(0)" ::: "memory");
    __builtin_amdgcn_s_barrier();

    #pragma unroll
    for (int kt = 0; kt < 5; ++kt) {
      const unsigned short* Ab = &SB[(kt & 1) * 2 * 128 * LDS2];
      const unsigned short* Bb = Ab + 128 * LDS2;
      __builtin_amdgcn_s_setprio(1);
      #pragma unroll
      for (int ks = 0; ks < 2; ++ks) {
        const int ko = ks * 32 + kg;
        bf16x8 ah[2], bh[4];
        #pragma unroll
        for (int mm = 0; mm < 2; ++mm)
          ah[mm] = *(const bf16x8*)&Ab[(wr + mm * 16 + r15) * LDS2 + ko];
        #pragma unroll
        for (int n = 0; n < 4; ++n)
          bh[n] = *(const bf16x8*)&Bb[(wc + n * 16 + r15) * LDS2 + ko];
        #pragma unroll
        for (int mm = 0; mm < 2; ++mm)
          #pragma unroll
          for (int n = 0; n < 4; ++n)
            acc[mm][n] = __builtin_amdgcn_mfma_f32_16x16x32_bf16(ah[mm], bh[n], acc[mm][n], 0, 0, 0);
      }
      __builtin_amdgcn_s_setprio(0);
      if (kt < 4) {
        if ((kt & 1) == 0) {
          WRITET(1, rB)
          if (kt + 2 <= 4) LOADT(rA, kt + 2)
        } else {
          WRITET(0, rA)
          if (kt + 2 <= 4) LOADT(rB, kt + 2)
        }
      }
      asm volatile("s_waitcnt lgkmcnt(0)" ::: "memory");
      __builtin_amdgcn_s_barrier();
    }
#undef LOADT
#undef WRITET
    const int rg = (lane >> 4) * 4;
    #pragma unroll
    for (int mm = 0; mm < 2; ++mm)
      #pragma unroll
      for (int n = 0; n < 4; ++n)
        #pragma unroll
        for (int r = 0; r < 4; ++r)
          atomicAdd(&S[(i0 + wr + mm * 16 + rg + r) * 256 + (j0 + wc + n * 16 + r15)],
                    acc[mm][n][r]);
  } else if (b < 288) {
    if (t < 256) {
      size_t idx = (size_t)(b - 256) * 2048 + t * 8;
      float s1[8] = {}, s2[8] = {};
      #pragma unroll 2
      for (int z = 0; z < 16; ++z) {
        u16x8 ha = *(const u16x8*)&Pc_part[(size_t)z * 65536 + idx];
        u16x8 hb = *(const u16x8*)&Pc_part[(size_t)(16 + z) * 65536 + idx];
        #pragma unroll
        for (int u = 0; u < 8; ++u) { s1[u] += bf2f(ha[u]); s2[u] += bf2f(hb[u]); }
      }
      float lam = scal[0];
      #pragma unroll
      for (int u = 0; u < 8; ++u) Pc[idx + u] = s1[u] - lam * s2[u];
    }
  } else if (b < 290) {
    if (t < 256) {
      const float* src = (b == 288) ? skp : svp;
      float s = 0.f;
      for (int z = 0; z < 320; ++z) s += src[z * 256 + t];
      if (b == 288) sk[t] = s; else sv[t] = s;
    }
  } else {
    if (t < 256) {
      int bb = b - 290, lane = t & 63, w = t >> 6;
      bool dogc = bb < 16;
      const float* A1 = dogc ? Wk1 : Wq1;
      const float* A2 = dogc ? Wk2 : Wq2;
      const float* x1 = dogc ? bq1 : bk1;
      const float* x2 = dogc ? bq2 : bk2;
      float* outv = dogc ? gc : uc;
      float lam = scal[0];
      int rb = (bb & 15) * 16 + w * 4;
      for (int q2 = 0; q2 < 4; ++q2) {
        int row = rb + q2;
        float s1 = 0.f, s2 = 0.f;
        #pragma unroll
        for (int c = 0; c < 8; ++c) {
          int kk2 = c * 256 + lane * 4;
          f32x4 a1 = *(const f32x4*)&A1[(size_t)row * HD + kk2];
          f32x4 a2 = *(const f32x4*)&A2[(size_t)row * HD + kk2];
          f32x4 v1 = *(const f32x4*)&x1[kk2];
          f32x4 v2 = *(const f32x4*)&x2[kk2];
          #pragma unroll
          for (int u = 0; u < 4; ++u) { s1 += a1[u] * v1[u]; s2 += a2[u] * v2[u]; }
        }
        WRED(s1); WRED(s2);
        if (lane == 0) outv[row] = s1 - lam * s2;
      }
    }
  }
}

// Ac = Pc @ S ; tc = Pc @ sk ; rv = S^T gc ; alpha_c = gc . sk
__global__ __launch_bounds__(256) void k_ac(
    const float* __restrict__ Pc, const float* __restrict__ S,
    const float* __restrict__ gc, const float* __restrict__ sk,
    float* __restrict__ Ac, float* __restrict__ tc, float* __restrict__ rv,
    float* __restrict__ scal) {
  int b = blockIdx.x, t = threadIdx.x;
  if (b < 32) {
    __shared__ float Pt[32][68];
    __shared__ float St[64][68];
    int i0 = (b >> 2) * 32, j0 = (b & 3) * 64;
    int ti = t >> 5, tj = t & 31;
    float acc[4][2] = {};
    for (int kt = 0; kt < 256; kt += 64) {
      __syncthreads();
      {
        int rr = t >> 3, c8 = (t & 7) * 8;
        *(f32x4*)&Pt[rr][c8] = *(const f32x4*)&Pc[(i0 + rr) * 256 + kt + c8];
        *(f32x4*)&Pt[rr][c8 + 4] = *(const f32x4*)&Pc[(i0 + rr) * 256 + kt + c8 + 4];
      }
      {
        int rr = t >> 2, c16 = (t & 3) * 16;
        #pragma unroll
        for (int c = 0; c < 4; ++c)
          *(f32x4*)&St[rr][c16 + c * 4] = *(const f32x4*)&S[(kt + rr) * 256 + j0 + c16 + c * 4];
      }
      __syncthreads();
      #pragma unroll 8
      for (int k2 = 0; k2 < 64; ++k2) {
        float a[4];
        #pragma unroll
        for (int u = 0; u < 4; ++u) a[u] = Pt[ti * 4 + u][k2];
        f32x2 b2 = *(const f32x2*)&St[k2][tj * 2];
        #pragma unroll
        for (int u = 0; u < 4; ++u) { acc[u][0] += a[u] * b2[0]; acc[u][1] += a[u] * b2[1]; }
      }
    }
    #pragma unroll
    for (int u = 0; u < 4; ++u) {
      Ac[(i0 + ti * 4 + u) * 256 + j0 + tj * 2] = acc[u][0];
      Ac[(i0 + ti * 4 + u) * 256 + j0 + tj * 2 + 1] = acc[u][1];
    }
  } else if (b == 32) {
    int lane = t & 63, w = t >> 6;
    f32x4 sk4 = *(const f32x4*)&sk[lane * 4];
    for (int ii = 0; ii < 64; ++ii) {
      int i = w * 64 + ii;
      f32x4 p4 = *(const f32x4*)&Pc[i * 256 + lane * 4];
      float s = p4[0] * sk4[0] + p4[1] * sk4[1] + p4[2] * sk4[2] + p4[3] * sk4[3];
      WRED(s);
      if (lane == 0) tc[i] = s;
    }
  } else {
    float s0 = 0.f, s1 = 0.f, s2 = 0.f, s3 = 0.f;
    #pragma unroll 4
    for (int i = 0; i < 256; i += 4) {
      s0 += gc[i] * S[i * 256 + t];
      s1 += gc[i + 1] * S[(i + 1) * 256 + t];
      s2 += gc[i + 2] * S[(i + 2) * 256 + t];
      s3 += gc[i + 3] * S[(i + 3) * 256 + t];
    }
    rv[t] = (s0 + s1) + (s2 + s3);
    if (t < 64) {
      f32x4 g4 = *(const f32x4*)&gc[t * 4];
      f32x4 sk4 = *(const f32x4*)&sk[t * 4];
      float a = g4[0] * sk4[0] + g4[1] * sk4[1] + g4[2] * sk4[2] + g4[3] * sk4[3];
      WRED(a);
      if (t == 0) scal[5] = a;
    }
  }
}

// Gc = Ac @ Wv + tc bv^T + uc (w + N bv)^T ; computes w/cc in-block
__global__ __launch_bounds__(256) void k_gc(
    const float* __restrict__ Ac, const float* __restrict__ Wv,
    const float* __restrict__ tc, const float* __restrict__ uc,
    const float* __restrict__ sv, const float* __restrict__ rv,
    const float* __restrict__ bv, const float* __restrict__ scal,
    float* __restrict__ Gc, float* __restrict__ cc) {
  __shared__ float At[64][68];
  __shared__ float Bt[64][132];
  __shared__ float svr[256], rvr[256];
  int t = threadIdx.x;
  int i0 = blockIdx.x * 64, j0 = blockIdx.y * 128;
  int ti = t >> 5, tj = t & 31;
  svr[t] = sv[t]; rvr[t] = rv[t];
  float acc[8][4] = {};
  f32x4 swa = {0.f, 0.f, 0.f, 0.f}, sca = {0.f, 0.f, 0.f, 0.f};
  for (int kt = 0; kt < 256; kt += 64) {
    __syncthreads();
    {
      int rr = t >> 2, c16 = (t & 3) * 16;
      #pragma unroll
      for (int c = 0; c < 4; ++c)
        *(f32x4*)&At[rr][c16 + c * 4] = *(const f32x4*)&Ac[(i0 + rr) * 256 + kt + c16 + c * 4];
    }
    {
      int rr = t >> 2, c32 = (t & 3) * 32;
      #pragma unroll
      for (int c = 0; c < 8; ++c)
        *(f32x4*)&Bt[rr][c32 + c * 4] = *(const f32x4*)&Wv[(size_t)(kt + rr) * HD + j0 + c32 + c * 4];
    }
    __syncthreads();
    #pragma unroll 8
    for (int k2 = 0; k2 < 64; ++k2) {
      float a[8];
      #pragma unroll
      for (int u = 0; u < 8; ++u) a[u] = At[ti * 8 + u][k2];
      f32x4 b = *(const f32x4*)&Bt[k2][tj * 4];
      float svk = svr[kt + k2], rvk = rvr[kt + k2];
      swa += b * svk; sca += b * rvk;
      #pragma unroll
      for (int u = 0; u < 8; ++u)
        #pragma unroll
        for (int v = 0; v < 4; ++v) acc[u][v] += a[u] * b[v];
    }
  }
  int j = j0 + tj * 4;
  f32x4 bv4 = *(const f32x4*)&bv[j];
  f32x4 wnb;
  #pragma unroll
  for (int v = 0; v < 4; ++v) wnb[v] = swa[v] + 20000.0f * bv4[v];
  if (blockIdx.x == 0 && ti == 0) {
    float ac = scal[5], dc = scal[4];
    f32x4 ccv;
    #pragma unroll
    for (int v = 0; v < 4; ++v) ccv[v] = sca[v] + ac * bv4[v] + dc * wnb[v];
    *(f32x4*)&cc[j] = ccv;
  }
  #pragma unroll
  for (int u = 0; u < 8; ++u) {
    int i = i0 + ti * 8 + u;
    float tci = tc[i], uci = uc[i];
    f32x4 o;
    #pragma unroll
    for (int v = 0; v < 4; ++v)
      o[v] = acc[u][v] + tci * bv4[v] + uci * wnb[v];
    *(f32x4*)&Gc[(size_t)i * HD + j] = o;
  }
}

// merged: [0,17) scal2 | [17,81) M = Gc Gc^T 64x64 tiles | [81,225) Hc partials
__global__ __launch_bounds__(256) void k_post(
    const float* __restrict__ Gc, const float* __restrict__ cc,
    const float* __restrict__ Wo, const float* __restrict__ g,
    const float* __restrict__ lnb, const float* __restrict__ scal_c,
    unsigned short* __restrict__ Bt2, float* __restrict__ M_part,
    float* __restrict__ Hc_part, float* __restrict__ scal) {
  __shared__ float SMEM[8768];
  int b = blockIdx.x, t = threadIdx.x;
  if (b < 17) {
    int lane = t & 63, w = t >> 6;
    if (b < 16) {
      int rb = b * 16 + w * 4;
      for (int q2 = 0; q2 < 4; ++q2) {
        int row = rb + q2;
        float s1 = 0.f, s2 = 0.f;
        #pragma unroll
        for (int c = 0; c < 8; ++c) {
          int kk2 = c * 256 + lane * 4;
          f32x4 g4 = *(const f32x4*)&Gc[(size_t)row * HD + kk2];
          f32x4 c4v = *(const f32x4*)&cc[kk2];
          #pragma unroll
          for (int u = 0; u < 4; ++u) { s1 += g4[u]; s2 += g4[u] * c4v[u]; }
        }
        WRED(s1); WRED(s2);
        if (lane == 0) {
          int base = ((256 + (row >> 5)) * 64 + ((row >> 3) & 3) * 16) * 8 + (row & 7);
          Bt2[base] = fbits(s1 * (1.0f / 2048.0f));
          Bt2[base + 8] = fbits(s2);
        }
      }
    } else {
      float s1 = 0.f, s2 = 0.f;
      #pragma unroll
      for (int c = 0; c < 2; ++c) {
        f32x4 v = *(const f32x4*)&cc[t * 8 + c * 4];
        #pragma unroll
        for (int u = 0; u < 4; ++u) { s1 += v[u]; s2 += v[u] * v[u]; }
      }
      WRED(s1); WRED(s2);
      if ((t & 63) == 0) { SMEM[t >> 6] = s1; SMEM[4 + (t >> 6)] = s2; }
      __syncthreads();
      if (t == 0) {
        scal[6] = SMEM[4] + SMEM[5] + SMEM[6] + SMEM[7];
        scal[7] = (SMEM[0] + SMEM[1] + SMEM[2] + SMEM[3]) * (1.0f / 2048.0f);
      }
      for (int idx = t; idx < 14 * 256; idx += 256) {
        int ci = idx >> 8, kk2 = idx & 255;
        int col = 514 + ci;
        Bt2[((256 + (kk2 >> 5)) * 64 + ((kk2 >> 3) & 3) * 16 + (col & 15)) * 8 + (kk2 & 7)] = 0;
      }
    }
  } else if (b < 81) {
    float (*Gi)[68] = (float(*)[68])SMEM;
    float (*Gj)[69] = (float(*)[69])(SMEM + 64 * 68);
    int idx = b - 17;
    int bx = idx & 3, by = (idx >> 2) & 3, z = idx >> 4;
    int i0 = bx * 64, j0 = by * 64;
    int ti = t >> 5, tj = t & 31;
    float acc[8][2] = {};
    for (int kt = 0; kt < 512; kt += 64) {
      int kb = z * 512 + kt;
      __syncthreads();
      {
        int rr = t >> 2, c16 = (t & 3) * 16;
        #pragma unroll
        for (int c = 0; c < 4; ++c) {
          *(f32x4*)&Gi[rr][c16 + c * 4] = *(const f32x4*)&Gc[(size_t)(i0 + rr) * HD + kb + c16 + c * 4];
          *(f32x4*)&Gj[rr][c16 + c * 4] = *(const f32x4*)&Gc[(size_t)(j0 + rr) * HD + kb + c16 + c * 4];
        }
      }
      __syncthreads();
      #pragma unroll 8
      for (int k2 = 0; k2 < 64; ++k2) {
        float a[8];
        #pragma unroll
        for (int u = 0; u < 8; ++u) a[u] = Gi[ti * 8 + u][k2];
        float b0 = Gj[tj * 2][k2], b1 = Gj[tj * 2 + 1][k2];
        #pragma unroll
        for (int u = 0; u < 8; ++u) { acc[u][0] += a[u] * b0; acc[u][1] += a[u] * b1; }
      }
    }
    #pragma unroll
    for (int u = 0; u < 8; ++u) {
      M_part[(size_t)z * 65536 + (i0 + ti * 8 + u) * 256 + j0 + tj * 2] = acc[u][0];
      M_part[(size_t)z * 65536 + (i0 + ti * 8 + u) * 256 + j0 + tj * 2 + 1] = acc[u][1];
    }
  } else {
    float (*At)[68] = (float(*)[68])SMEM;
    float (*Bt)[68] = (float(*)[68])(SMEM + 32 * 68);
    int idx = b - 81;
    int bx = idx % 9, rem = idx / 9, by = rem & 3, z = rem >> 2;
    int i0 = bx * 32, j0 = by * 64;
    float s2 = scal_c[2];
    int ti = t >> 5, tj = t & 31;
    float acc[4][2] = {};
    for (int kt = 0; kt < 512; kt += 64) {
      int kb = z * 512 + kt;
      __syncthreads();
      {
        int rr = t >> 3, c8 = (t & 7) * 8, gi = i0 + rr;
        #pragma unroll
        for (int h = 0; h < 8; h += 4) {
          f32x4 g4 = *(const f32x4*)&g[kb + c8 + h];
          f32x4 a;
          if (gi < 256) {
            f32x4 gg = *(const f32x4*)&Gc[(size_t)gi * HD + kb + c8 + h];
            #pragma unroll
            for (int u = 0; u < 4; ++u) a[u] = gg[u] * g4[u];
          } else if (gi == 256) {
            a = g4;
          } else if (gi == 257) {
            f32x4 c4v = *(const f32x4*)&cc[kb + c8 + h];
            #pragma unroll
            for (int u = 0; u < 4; ++u) a[u] = c4v[u] * g4[u];
          } else if (gi == 258) {
            a = *(const f32x4*)&lnb[kb + c8 + h];
          } else {
            a = (f32x4){0.f, 0.f, 0.f, 0.f};
          }
          *(f32x4*)&At[rr][c8 + h] = a;
        }
      }
      {
        int rr = t >> 2, c16 = (t & 3) * 16;
        #pragma unroll
        for (int c = 0; c < 4; ++c) {
          f32x4 bb = *(const f32x4*)&Wo[(size_t)(kb + rr) * 256 + j0 + c16 + c * 4];
          #pragma unroll
          for (int u = 0; u < 4; ++u) bb[u] *= s2;
          *(f32x4*)&Bt[rr][c16 + c * 4] = bb;
        }
      }
      __syncthreads();
      #pragma unroll 8
      for (int k2 = 0; k2 < 64; ++k2) {
        float a[4];
        #pragma unroll
        for (int u = 0; u < 4; ++u) a[u] = At[ti * 4 + u][k2];
        f32x2 b2 = *(const f32x2*)&Bt[k2][tj * 2];
        #pragma unroll
        for (int u = 0; u < 4; ++u) { acc[u][0] += a[u] * b2[0]; acc[u][1] += a[u] * b2[1]; }
      }
    }
    #pragma unroll
    for (int u = 0; u < 4; ++u) {
      Hc_part[(size_t)z * 73728 + (i0 + ti * 4 + u) * 256 + j0 + tj * 2] = acc[u][0];
      Hc_part[(size_t)z * 73728 + (i0 + ti * 4 + u) * 256 + j0 + tj * 2 + 1] = acc[u][1];
    }
  }
}

// reduce M/Hc partials -> Bt2 (wave-contiguous bf16); vectors wbar/hc/bc
__global__ __launch_bounds__(256) void k_red2(
    const float* __restrict__ M_part, const float* __restrict__ Hc_part,
    const float* __restrict__ bo, unsigned short* __restrict__ Bt2,
    float* __restrict__ wbar, float* __restrict__ hcv, float* __restrict__ bcv) {
  int bi = blockIdx.x, z2 = blockIdx.y, t = threadIdx.x;
  if (z2 == 2) {
    if (bi != 0) return;
    float s0 = 0.f, s1 = 0.f, s2 = 0.f;
    #pragma unroll
    for (int z = 0; z < 4; ++z) {
      s0 += Hc_part[(size_t)z * 73728 + 256 * 256 + t];
      s1 += Hc_part[(size_t)z * 73728 + 257 * 256 + t];
      s2 += Hc_part[(size_t)z * 73728 + 258 * 256 + t];
    }
    wbar[t] = s0; hcv[t] = s1; bcv[t] = s2 + bo[t];
    return;
  }
  __shared__ unsigned short T[64][256];
  const float* src = z2 ? Hc_part : M_part;
  const size_t sp = z2 ? 73728 : 65536;
  const int base = z2 ? 256 : 0;
  for (int ii = 0; ii < 64; ++ii) {
    int i = bi * 64 + ii;
    float s = 0.f;
    #pragma unroll
    for (int z = 0; z < 4; ++z) s += src[z * sp + i * 256 + t];
    T[ii][t] = fbits(s);
  }
  __syncthreads();
  const int col = base + t;
  #pragma unroll
  for (int c = 0; c < 64; c += 8) {
    u16x8 o;
    #pragma unroll
    for (int u = 0; u < 8; ++u) o[u] = T[c + u][t];
    int kk0 = bi * 64 + c;
    int addr = (((col >> 4) * 8 + (kk0 >> 5)) * 64 + ((kk0 >> 3) & 3) * 16 + (col & 15)) * 8;
    *(u16x8*)&Bt2[addr] = o;
  }
}

// fused final (512 thr, 8 waves, 64 cols/wave): y|z|mu|m2 = q @ Bt2 + LN epilogue
__global__ __launch_bounds__(512) void k_out(
    const float* __restrict__ q, const unsigned short* __restrict__ Bt2,
    const float* __restrict__ hcv, const float* __restrict__ wbar,
    const float* __restrict__ bcv, const float* __restrict__ scal,
    float* __restrict__ out) {
  __shared__ unsigned short As[32 * 264];
  __shared__ unsigned short zbuf[32][264];
  __shared__ float sqp[4][32];
  __shared__ float muL[32], m2L[32];
  const int t = threadIdx.x, lane = t & 63, wave = t >> 6;
  const int row0 = blockIdx.x * 32;
  const int r15 = lane & 15, kg = lane >> 4;
  {
    #pragma unroll
    for (int i = 0; i < 4; ++i) {
      int ch = i * 512 + t;
      int row = ch >> 6, c4 = (ch & 63) * 4;
      f32x4 v = *(const f32x4*)&q[(size_t)(row0 + row) * HIW + c4];
      bf16x4v o;
      #pragma unroll
      for (int u = 0; u < 4; ++u) o[u] = (__bf16)v[u];
      *(bf16x4v*)&As[row * 264 + c4] = o;
    }
  }
  __syncthreads();
  const bool isM = wave < 4;
  const int wcol = isM ? wave * 64 : 256 + (wave - 4) * 64;
  const int grp0 = wcol >> 4;
  f32x4 acc[2][5];
  #pragma unroll
  for (int m = 0; m < 2; ++m)
    #pragma unroll
    for (int n = 0; n < 5; ++n) acc[m][n] = (f32x4){0.f, 0.f, 0.f, 0.f};
  __builtin_amdgcn_s_setprio(1);
  #pragma unroll
  for (int ko = 0; ko < 8; ++ko) {
    bf16x8 af0 = *(const bf16x8*)&As[r15 * 264 + ko * 32 + kg * 8];
    bf16x8 af1 = *(const bf16x8*)&As[(16 + r15) * 264 + ko * 32 + kg * 8];
    #pragma unroll
    for (int ni = 0; ni < 5; ++ni) {
      if (ni == 4 && wave != 7) continue;
      const int grp = (ni == 4) ? 32 : grp0 + ni;
      bf16x8 bfr = *(const bf16x8*)&Bt2[(size_t)(grp * 8 + ko) * 512 + lane * 8];
      acc[0][ni] = __builtin_amdgcn_mfma_f32_16x16x32_bf16(af0, bfr, acc[0][ni], 0, 0, 0);
      acc[1][ni] = __builtin_amdgcn_mfma_f32_16x16x32_bf16(af1, bfr, acc[1][ni], 0, 0, 0);
    }
  }
  __builtin_amdgcn_s_setprio(0);
  if (isM) {
    #pragma unroll
    for (int m = 0; m < 2; ++m)
      #pragma unroll
      for (int r = 0; r < 4; ++r) {
        int rowl = m * 16 + kg * 4 + r;
        float p = 0.f;
        #pragma unroll
        for (int ni = 0; ni < 4; ++ni) {
          int col = wcol + ni * 16 + r15;
          p += acc[m][ni][r] * bf2f(As[rowl * 264 + col]);
        }
        p += __shfl_xor(p, 1); p += __shfl_xor(p, 2);
        p += __shfl_xor(p, 4); p += __shfl_xor(p, 8);
        if (r15 == 0) sqp[wave][rowl] = p;
      }
  } else {
    #pragma unroll
    for (int m = 0; m < 2; ++m)
      #pragma unroll
      for (int r = 0; r < 4; ++r) {
        int rowl = m * 16 + kg * 4 + r;
        #pragma unroll
        for (int ni = 0; ni < 4; ++ni)
          zbuf[rowl][(wcol - 256) + ni * 16 + r15] = fbits(acc[m][ni][r]);
      }
    if (wave == 7) {
      #pragma unroll
      for (int m = 0; m < 2; ++m)
        #pragma unroll
        for (int r = 0; r < 4; ++r) {
          int rowl = m * 16 + kg * 4 + r;
          if (r15 == 0) muL[rowl] = acc[m][4][r];
          if (r15 == 1) m2L[rowl] = acc[m][4][r];
        }
    }
  }
  __syncthreads();
  const float css = scal[6], cbar = scal[7];
  #pragma unroll
  for (int i = 0; i < 4; ++i) {
    const int row = i * 8 + wave;
    const int c4 = lane * 4;
    float mu = muL[row] + cbar;
    float ss = (sqp[0][row] + sqp[1][row]) + (sqp[2][row] + sqp[3][row]) +
               2.0f * m2L[row] + css;
    float var = ss * (1.0f / 2048.0f) - mu * mu;
    float rstd = rsqrtf(var + 1e-5f);
    u16x4 zh = *(const u16x4*)&zbuf[row][c4];
    f32x4 h4 = *(const f32x4*)&hcv[c4];
    f32x4 w4 = *(const f32x4*)&wbar[c4];
    f32x4 b4 = *(const f32x4*)&bcv[c4];
    f32x4 o;
    #pragma unroll
    for (int u = 0; u < 4; ++u)
      o[u] = rstd * (bf2f(zh[u]) + h4[u] - mu * w4[u]) + b4[u];
    *(f32x4*)&out[(size_t)(row0 + row) * HIW + c4] = o;
  }
}

extern "C" void kernel_launch(void* const* d_in, const int* in_sizes, int n_in,
                              void* d_out, int out_size, void* d_ws, size_t ws_size,
                              hipStream_t stream) {
  const float* q   = (const float*)d_in[0];
  const float* k   = (const float*)d_in[1];
  const float* v   = (const float*)d_in[2];
  const int* layer = (const int*)d_in[3];
  const float* Wq1 = (const float*)d_in[4];  const float* bq1 = (const float*)d_in[5];
  const float* Wk1 = (const float*)d_in[6];  const float* bk1 = (const float*)d_in[7];
  const float* Wq2 = (const float*)d_in[8];  const float* bq2 = (const float*)d_in[9];
  const float* Wk2 = (const float*)d_in[10]; const float* bk2 = (const float*)d_in[11];
  const float* Wv  = (const float*)d_in[12]; const float* bv  = (const float*)d_in[13];
  const float* lng = (const float*)d_in[14]; const float* lnb = (const float*)d_in[15];
  const float* Wo  = (const float*)d_in[16]; const float* bo  = (const float*)d_in[17];
  const float* lq1 = (const float*)d_in[18]; const float* lk1 = (const float*)d_in[19];
  const float* lq2 = (const float*)d_in[20]; const float* lk2 = (const float*)d_in[21];

  char* p = (char*)d_ws;
  unsigned short* kT = (unsigned short*)p;
  float* M_part  = (float*)p;
  float* Hc_part = (float*)(p + 1048576);
  unsigned short* Bt2 = (unsigned short*)(p + 1048576 + 1179648);
  p += (size_t)256 * NTP * 2;
  unsigned short* vT = (unsigned short*)p;
  float* Gc = (float*)p;
  p += (size_t)256 * NTP * 2;
  float* skp = (float*)p;     p += (size_t)320 * 256 * 4;
  float* svp = (float*)p;     p += (size_t)320 * 256 * 4;
  unsigned short* Pc_part = (unsigned short*)p; p += (size_t)32 * 65536 * 2;
  float* S  = (float*)p;      p += 65536 * 4;
  float* Pc = (float*)p;      p += 65536 * 4;
  float* sk = (float*)p;      p += 1024;
  float* sv = (float*)p;      p += 1024;
  float* gc = (float*)p;      p += 1024;
  float* uc = (float*)p;      p += 1024;
  float* tc = (float*)p;      p += 1024;
  float* rv = (float*)p;      p += 1024;
  float* cc = (float*)p;      p += 2048 * 4;
  float* Ac = (float*)p;      p += 65536 * 4;
  float* wbar = (float*)p;    p += 1024;
  float* hcv  = (float*)p;    p += 1024;
  float* bcv  = (float*)p;    p += 1024;
  float* scal = (float*)p;    p += 256;

  const dim3 b256(256);
  k_front<<<dim3(770), b256, 0, stream>>>(k, v, Wq1, Wk1, Wq2, Wk2,
      lq1, lk1, lq2, lk2, bq1, bk1, bq2, bk2, layer, kT, vT, skp, svp, Pc_part, scal, S);
  k_mid<<<dim3(322), dim3(512), 0, stream>>>(kT, vT, S, Pc_part, skp, svp, Pc, sk, sv,
      Wk1, Wk2, Wq1, Wq2, bq1, bq2, bk1, bk2, scal, gc, uc);
  k_ac<<<dim3(34), b256, 0, stream>>>(Pc, S, gc, sk, Ac, tc, rv, scal);
  k_gc<<<dim3(4, 16), b256, 0, stream>>>(Ac, Wv, tc, uc, sv, rv, bv, scal, Gc, cc);
  k_post<<<dim3(225), b256, 0, stream>>>(Gc, cc, Wo, lng, lnb, scal, Bt2, M_part, Hc_part, scal);
  k_red2<<<dim3(4, 3), b256, 0, stream>>>(M_part, Hc_part, bo, Bt2, wbar, hcv, bcv);
  k_out<<<dim3(625), dim3(512), 0, stream>>>(q, Bt2, hcv, wbar, bcv, scal, (float*)d_out);
}

// Round 17
// 162.705 us; speedup vs baseline: 1.1750x; 1.0373x over previous
//
#include <hip/hip_runtime.h>
#include <stdint.h>

typedef __bf16 bf16x8 __attribute__((ext_vector_type(8)));
typedef __bf16 bf16x4v __attribute__((ext_vector_type(4)));
typedef float f32x4 __attribute__((ext_vector_type(4)));
typedef float f32x2 __attribute__((ext_vector_type(2)));
typedef unsigned short u16x4 __attribute__((ext_vector_type(4)));
typedef unsigned short u16x8 __attribute__((ext_vector_type(8)));

#define NTOK 20000
#define NTP  20480
#define HIW  256
#define HD   2048
#define LDKP 66
#define LDS2 72
#define TSZ  16384   // shorts per kT/vT tile: 256 cols x 64 toks
#define LTC  272     // k_tc LDS row stride (shorts)

static __device__ __forceinline__ float bf2f(unsigned short h) {
  union { unsigned u; float f; } c; c.u = ((unsigned)h) << 16;
  return c.f;
}
static __device__ __forceinline__ unsigned short fbits(float x) {
  __bf16 h = (__bf16)x;
  return __builtin_bit_cast(unsigned short, h);
}

#define WRED(x) { x += __shfl_xor(x,32); x += __shfl_xor(x,16); x += __shfl_xor(x,8); \
                  x += __shfl_xor(x,4);  x += __shfl_xor(x,2);  x += __shfl_xor(x,1); }

// Bt2 layout: (col,kk) -> addr = (((col>>4)*8 + (kk>>5))*64 + ((kk>>3)&3)*16 + (col&15))*8 + (kk&7)
// kT/vT layout: tile-major [tile][col][64]

// ===== k_front (256 thr): [0,640) k_tc (bf16 LDS) | [640,768) k_pc | 768 lambda | 769 zero-S =====
__global__ __launch_bounds__(256) void k_front(
    const float* __restrict__ kk, const float* __restrict__ vv,
    const float* __restrict__ Wq1, const float* __restrict__ Wk1,
    const float* __restrict__ Wq2, const float* __restrict__ Wk2,
    const float* __restrict__ lq1, const float* __restrict__ lk1,
    const float* __restrict__ lq2, const float* __restrict__ lk2,
    const float* __restrict__ bq1, const float* __restrict__ bk1,
    const float* __restrict__ bq2, const float* __restrict__ bk2,
    const int* __restrict__ layer,
    unsigned short* __restrict__ kT, unsigned short* __restrict__ vT,
    float* __restrict__ skp, float* __restrict__ svp,
    unsigned short* __restrict__ Pc_part, float* __restrict__ scal,
    float* __restrict__ S) {
  __shared__ unsigned short SMEM[64 * LTC];   // 34816 B -> 4 blocks/CU
  const int b = blockIdx.x, t = threadIdx.x;

  if (b < 640) {
    const int tile = b >> 1, m = b & 1;
    const float* src = m ? vv : kk;
    unsigned short* dstT = m ? vT : kT;
    float* sump = m ? svp : skp;
    #pragma unroll
    for (int i = 0; i < 16; ++i) {
      int ch = i * 256 + t;
      int row = ch >> 6, c4 = (ch & 63) * 4;
      int gtok = tile * 64 + row;
      f32x4 val = {0.f, 0.f, 0.f, 0.f};
      if (gtok < NTOK) val = *(const f32x4*)&src[(size_t)gtok * HIW + c4];
      bf16x4v o;
      #pragma unroll
      for (int u = 0; u < 4; ++u) o[u] = (__bf16)val[u];
      *(bf16x4v*)&SMEM[row * LTC + c4] = o;
    }
    __syncthreads();
    float sum = 0.f;
    unsigned short cv[64];
    #pragma unroll
    for (int tok = 0; tok < 64; ++tok) {
      unsigned short h = SMEM[tok * LTC + t];
      sum += bf2f(h);
      cv[tok] = h;
    }
    sump[tile * 256 + t] = sum;
    size_t base = (size_t)tile * TSZ + (size_t)t * 64;
    #pragma unroll
    for (int s = 0; s < 8; ++s)
      *(u16x8*)&dstT[base + s * 8] = *(const u16x8*)&cv[s * 8];
  } else if (b < 768) {
    // ---- Pc_part[pair*16+z] = Wa Wb^T K-slice (bf16 partials) ----
    unsigned short* Ak = SMEM;
    unsigned short* Bk = Ak + 128 * LDKP;
    const int idx = b - 640;
    const int pair = idx >> 6, rem = idx & 63;
    const int z = rem & 15, by = (rem >> 4) & 1, bx = (rem >> 5) & 1;
    const int i0 = bx * 128, j0 = by * 128;
    const int lane = t & 63, wave = t >> 6;
    const int wr = (wave >> 1) * 64, wc = (wave & 1) * 64;
    const int r15 = lane & 15, kg = (lane >> 4) * 8;
    const float* Wa = pair ? Wq2 : Wq1;
    const float* Wb = pair ? Wk2 : Wk1;
    f32x4 acc[4][4];
    #pragma unroll
    for (int m = 0; m < 4; ++m)
      #pragma unroll
      for (int n = 0; n < 4; ++n) acc[m][n] = (f32x4){0.f, 0.f, 0.f, 0.f};
    const int srow = t >> 1, sh = (t & 1) * 32;
    for (int kt = 0; kt < 2; ++kt) {
      const int kb = z * 128 + kt * 64 + sh;
      __syncthreads();
      #pragma unroll
      for (int c = 0; c < 8; ++c) {
        f32x4 a = *(const f32x4*)&Wa[(size_t)(i0 + srow) * HD + kb + c * 4];
        f32x4 bb = *(const f32x4*)&Wb[(size_t)(j0 + srow) * HD + kb + c * 4];
        bf16x4v oa, ob;
        #pragma unroll
        for (int u = 0; u < 4; ++u) { oa[u] = (__bf16)a[u]; ob[u] = (__bf16)bb[u]; }
        *(bf16x4v*)&Ak[srow * LDKP + sh + c * 4] = oa;
        *(bf16x4v*)&Bk[srow * LDKP + sh + c * 4] = ob;
      }
      __syncthreads();
      #pragma unroll
      for (int ks = 0; ks < 2; ++ks) {
        const int ko = ks * 32 + kg;
        bf16x8 ah[4], bh[4];
        #pragma unroll
        for (int m = 0; m < 4; ++m)
          ah[m] = *(const bf16x8*)&Ak[(wr + m * 16 + r15) * LDKP + ko];
        #pragma unroll
        for (int n = 0; n < 4; ++n)
          bh[n] = *(const bf16x8*)&Bk[(wc + n * 16 + r15) * LDKP + ko];
        #pragma unroll
        for (int m = 0; m < 4; ++m)
          #pragma unroll
          for (int n = 0; n < 4; ++n)
            acc[m][n] = __builtin_amdgcn_mfma_f32_16x16x32_bf16(ah[m], bh[n], acc[m][n], 0, 0, 0);
      }
    }
    const int rg = (lane >> 4) * 4;
    unsigned short* Pp = Pc_part + (size_t)(pair * 16 + z) * 65536;
    #pragma unroll
    for (int m = 0; m < 4; ++m)
      #pragma unroll
      for (int n = 0; n < 4; ++n)
        #pragma unroll
        for (int r = 0; r < 4; ++r)
          Pp[(i0 + wr + m * 16 + rg + r) * 256 + (j0 + wc + n * 16 + r15)] = fbits(acc[m][n][r]);
  } else if (b == 768) {
    float* red = (float*)SMEM;
    float p1 = lq1[t] * lk1[t], p2 = lq2[t] * lk2[t];
    float d1 = 0.f, d2 = 0.f;
    #pragma unroll
    for (int u = 0; u < 8; ++u) {
      d1 += bq1[t * 8 + u] * bk1[t * 8 + u];
      d2 += bq2[t * 8 + u] * bk2[t * 8 + u];
    }
    WRED(p1); WRED(p2); WRED(d1); WRED(d2);
    int w = t >> 6;
    if ((t & 63) == 0) { red[w] = p1; red[4 + w] = p2; red[8 + w] = d1; red[12 + w] = d2; }
    __syncthreads();
    if (t == 0) {
      float s1 = red[0] + red[1] + red[2] + red[3];
      float s2 = red[4] + red[5] + red[6] + red[7];
      float dd1 = red[8] + red[9] + red[10] + red[11];
      float dd2 = red[12] + red[13] + red[14] + red[15];
      float li = 0.8f - 0.6f * expf(-0.3f * (float)layer[0]);
      float lam = expf(s1) - expf(s2) + li;
      scal[0] = lam; scal[1] = -lam; scal[2] = 1.0f - li; scal[3] = li;
      scal[4] = dd1 - lam * dd2;
    }
  } else {
    const f32x4 z4 = {0.f, 0.f, 0.f, 0.f};
    #pragma unroll
    for (int i = 0; i < 64; ++i)
      *(f32x4*)&S[i * 1024 + t * 4] = z4;
  }
}

// ============ k_mid (512 thr): [0,256) S-GEMM(atomic) | [256,288) Pc-red |
//              [288,290) colsum-red | [290,322) gc/uc ============
__global__ __launch_bounds__(512) void k_mid(
    const unsigned short* __restrict__ kT, const unsigned short* __restrict__ vT,
    float* __restrict__ S, const unsigned short* __restrict__ Pc_part,
    const float* __restrict__ skp, const float* __restrict__ svp,
    float* __restrict__ Pc, float* __restrict__ sk, float* __restrict__ sv,
    const float* __restrict__ Wk1, const float* __restrict__ Wk2,
    const float* __restrict__ Wq1, const float* __restrict__ Wq2,
    const float* __restrict__ bq1, const float* __restrict__ bq2,
    const float* __restrict__ bk1, const float* __restrict__ bk2,
    const float* __restrict__ scal, float* __restrict__ gc, float* __restrict__ uc) {
  __shared__ unsigned short SB[2 * 2 * 128 * LDS2];
  const int b = blockIdx.x, t = threadIdx.x;

  if (b < 256) {
    const int z = b & 63, by = (b >> 6) & 1, bx = (b >> 7) & 1;
    const int i0 = bx * 128, j0 = by * 128;
    const int lane = t & 63, wave = t >> 6;
    const int wr = (wave >> 1) * 32, wc = (wave & 1) * 64;
    const int r15 = lane & 15, kg = (lane >> 4) * 8;
    const int m = t >> 8;
    const int local = t & 255;
    const int row2 = local >> 1;
    const int koff = (local & 1) * 32;
    const unsigned short* srcT = m ? vT : kT;
    const size_t tbase = (size_t)(5 * z) * TSZ + (size_t)((m ? j0 : i0) + row2) * 64 + koff;
    const int lds_off = m * 128 * LDS2 + row2 * LDS2 + koff;

    f32x4 acc[2][4];
    #pragma unroll
    for (int mm = 0; mm < 2; ++mm)
      #pragma unroll
      for (int n = 0; n < 4; ++n) acc[mm][n] = (f32x4){0.f, 0.f, 0.f, 0.f};
    u16x8 rA[4], rB[4];

#define LOADT(R, KT)                                                          \
    { _Pragma("unroll")                                                       \
      for (int c = 0; c < 4; ++c)                                             \
        R[c] = *(const u16x8*)&srcT[tbase + (size_t)(KT) * TSZ + c * 8]; }
#define WRITET(BUF, R)                                                        \
    { unsigned short* d = &SB[(BUF) * 2 * 128 * LDS2 + lds_off];              \
      _Pragma("unroll")                                                       \
      for (int c = 0; c < 4; ++c) *(u16x8*)&d[c * 8] = R[c]; }

    LOADT(rA, 0)
    WRITET(0, rA)
    LOADT(rB, 1)
    asm volatile("s_waitcnt lgkmcnt(0)" ::: "memory");
    __builtin_amdgcn_s_barrier();

    #pragma unroll
    for (int kt = 0; kt < 5; ++kt) {
      const unsigned short* Ab = &SB[(kt & 1) * 2 * 128 * LDS2];
      const unsigned short* Bb = Ab + 128 * LDS2;
      __builtin_amdgcn_s_setprio(1);
      #pragma unroll
      for (int ks = 0; ks < 2; ++ks) {
        const int ko = ks * 32 + kg;
        bf16x8 ah[2], bh[4];
        #pragma unroll
        for (int mm = 0; mm < 2; ++mm)
          ah[mm] = *(const bf16x8*)&Ab[(wr + mm * 16 + r15) * LDS2 + ko];
        #pragma unroll
        for (int n = 0; n < 4; ++n)
          bh[n] = *(const bf16x8*)&Bb[(wc + n * 16 + r15) * LDS2 + ko];
        #pragma unroll
        for (int mm = 0; mm < 2; ++mm)
          #pragma unroll
          for (int n = 0; n < 4; ++n)
            acc[mm][n] = __builtin_amdgcn_mfma_f32_16x16x32_bf16(ah[mm], bh[n], acc[mm][n], 0, 0, 0);
      }
      __builtin_amdgcn_s_setprio(0);
      if (kt < 4) {
        if ((kt & 1) == 0) {
          WRITET(1, rB)
          if (kt + 2 <= 4) LOADT(rA, kt + 2)
        } else {
          WRITET(0, rA)
          if (kt + 2 <= 4) LOADT(rB, kt + 2)
        }
      }
      asm volatile("s_waitcnt lgkmcnt(0)" ::: "memory");
      __builtin_amdgcn_s_barrier();
    }
#undef LOADT
#undef WRITET
    const int rg = (lane >> 4) * 4;
    #pragma unroll
    for (int mm = 0; mm < 2; ++mm)
      #pragma unroll
      for (int n = 0; n < 4; ++n)
        #pragma unroll
        for (int r = 0; r < 4; ++r)
          atomicAdd(&S[(i0 + wr + mm * 16 + rg + r) * 256 + (j0 + wc + n * 16 + r15)],
                    acc[mm][n][r]);
  } else if (b < 288) {
    if (t < 256) {
      size_t idx = (size_t)(b - 256) * 2048 + t * 8;
      float s1[8] = {}, s2[8] = {};
      #pragma unroll 2
      for (int z = 0; z < 16; ++z) {
        u16x8 ha = *(const u16x8*)&Pc_part[(size_t)z * 65536 + idx];
        u16x8 hb = *(const u16x8*)&Pc_part[(size_t)(16 + z) * 65536 + idx];
        #pragma unroll
        for (int u = 0; u < 8; ++u) { s1[u] += bf2f(ha[u]); s2[u] += bf2f(hb[u]); }
      }
      float lam = scal[0];
      #pragma unroll
      for (int u = 0; u < 8; ++u) Pc[idx + u] = s1[u] - lam * s2[u];
    }
  } else if (b < 290) {
    if (t < 256) {
      const float* src = (b == 288) ? skp : svp;
      float s = 0.f;
      for (int z = 0; z < 320; ++z) s += src[z * 256 + t];
      if (b == 288) sk[t] = s; else sv[t] = s;
    }
  } else {
    if (t < 256) {
      int bb = b - 290, lane = t & 63, w = t >> 6;
      bool dogc = bb < 16;
      const float* A1 = dogc ? Wk1 : Wq1;
      const float* A2 = dogc ? Wk2 : Wq2;
      const float* x1 = dogc ? bq1 : bk1;
      const float* x2 = dogc ? bq2 : bk2;
      float* outv = dogc ? gc : uc;
      float lam = scal[0];
      int rb = (bb & 15) * 16 + w * 4;
      for (int q2 = 0; q2 < 4; ++q2) {
        int row = rb + q2;
        float s1 = 0.f, s2 = 0.f;
        #pragma unroll
        for (int c = 0; c < 8; ++c) {
          int kk2 = c * 256 + lane * 4;
          f32x4 a1 = *(const f32x4*)&A1[(size_t)row * HD + kk2];
          f32x4 a2 = *(const f32x4*)&A2[(size_t)row * HD + kk2];
          f32x4 v1 = *(const f32x4*)&x1[kk2];
          f32x4 v2 = *(const f32x4*)&x2[kk2];
          #pragma unroll
          for (int u = 0; u < 4; ++u) { s1 += a1[u] * v1[u]; s2 += a2[u] * v2[u]; }
        }
        WRED(s1); WRED(s2);
        if (lane == 0) outv[row] = s1 - lam * s2;
      }
    }
  }
}

// Ac = Pc @ S ; tc = Pc @ sk ; rv = S^T gc ; alpha_c = gc . sk
__global__ __launch_bounds__(256) void k_ac(
    const float* __restrict__ Pc, const float* __restrict__ S,
    const float* __restrict__ gc, const float* __restrict__ sk,
    float* __restrict__ Ac, float* __restrict__ tc, float* __restrict__ rv,
    float* __restrict__ scal) {
  int b = blockIdx.x, t = threadIdx.x;
  if (b < 32) {
    __shared__ float Pt[32][68];
    __shared__ float St[64][68];
    int i0 = (b >> 2) * 32, j0 = (b & 3) * 64;
    int ti = t >> 5, tj = t & 31;
    float acc[4][2] = {};
    for (int kt = 0; kt < 256; kt += 64) {
      __syncthreads();
      {
        int rr = t >> 3, c8 = (t & 7) * 8;
        *(f32x4*)&Pt[rr][c8] = *(const f32x4*)&Pc[(i0 + rr) * 256 + kt + c8];
        *(f32x4*)&Pt[rr][c8 + 4] = *(const f32x4*)&Pc[(i0 + rr) * 256 + kt + c8 + 4];
      }
      {
        int rr = t >> 2, c16 = (t & 3) * 16;
        #pragma unroll
        for (int c = 0; c < 4; ++c)
          *(f32x4*)&St[rr][c16 + c * 4] = *(const f32x4*)&S[(kt + rr) * 256 + j0 + c16 + c * 4];
      }
      __syncthreads();
      #pragma unroll 8
      for (int k2 = 0; k2 < 64; ++k2) {
        float a[4];
        #pragma unroll
        for (int u = 0; u < 4; ++u) a[u] = Pt[ti * 4 + u][k2];
        f32x2 b2 = *(const f32x2*)&St[k2][tj * 2];
        #pragma unroll
        for (int u = 0; u < 4; ++u) { acc[u][0] += a[u] * b2[0]; acc[u][1] += a[u] * b2[1]; }
      }
    }
    #pragma unroll
    for (int u = 0; u < 4; ++u) {
      Ac[(i0 + ti * 4 + u) * 256 + j0 + tj * 2] = acc[u][0];
      Ac[(i0 + ti * 4 + u) * 256 + j0 + tj * 2 + 1] = acc[u][1];
    }
  } else if (b == 32) {
    int lane = t & 63, w = t >> 6;
    f32x4 sk4 = *(const f32x4*)&sk[lane * 4];
    for (int ii = 0; ii < 64; ++ii) {
      int i = w * 64 + ii;
      f32x4 p4 = *(const f32x4*)&Pc[i * 256 + lane * 4];
      float s = p4[0] * sk4[0] + p4[1] * sk4[1] + p4[2] * sk4[2] + p4[3] * sk4[3];
      WRED(s);
      if (lane == 0) tc[i] = s;
    }
  } else {
    float s0 = 0.f, s1 = 0.f, s2 = 0.f, s3 = 0.f;
    #pragma unroll 4
    for (int i = 0; i < 256; i += 4) {
      s0 += gc[i] * S[i * 256 + t];
      s1 += gc[i + 1] * S[(i + 1) * 256 + t];
      s2 += gc[i + 2] * S[(i + 2) * 256 + t];
      s3 += gc[i + 3] * S[(i + 3) * 256 + t];
    }
    rv[t] = (s0 + s1) + (s2 + s3);
    if (t < 64) {
      f32x4 g4 = *(const f32x4*)&gc[t * 4];
      f32x4 sk4 = *(const f32x4*)&sk[t * 4];
      float a = g4[0] * sk4[0] + g4[1] * sk4[1] + g4[2] * sk4[2] + g4[3] * sk4[3];
      WRED(a);
      if (t == 0) scal[5] = a;
    }
  }
}

// Gc = Ac @ Wv + tc bv^T + uc (w + N bv)^T ; computes w/cc in-block
__global__ __launch_bounds__(256) void k_gc(
    const float* __restrict__ Ac, const float* __restrict__ Wv,
    const float* __restrict__ tc, const float* __restrict__ uc,
    const float* __restrict__ sv, const float* __restrict__ rv,
    const float* __restrict__ bv, const float* __restrict__ scal,
    float* __restrict__ Gc, float* __restrict__ cc) {
  __shared__ float At[64][68];
  __shared__ float Bt[64][132];
  __shared__ float svr[256], rvr[256];
  int t = threadIdx.x;
  int i0 = blockIdx.x * 64, j0 = blockIdx.y * 128;
  int ti = t >> 5, tj = t & 31;
  svr[t] = sv[t]; rvr[t] = rv[t];
  float acc[8][4] = {};
  f32x4 swa = {0.f, 0.f, 0.f, 0.f}, sca = {0.f, 0.f, 0.f, 0.f};
  for (int kt = 0; kt < 256; kt += 64) {
    __syncthreads();
    {
      int rr = t >> 2, c16 = (t & 3) * 16;
      #pragma unroll
      for (int c = 0; c < 4; ++c)
        *(f32x4*)&At[rr][c16 + c * 4] = *(const f32x4*)&Ac[(i0 + rr) * 256 + kt + c16 + c * 4];
    }
    {
      int rr = t >> 2, c32 = (t & 3) * 32;
      #pragma unroll
      for (int c = 0; c < 8; ++c)
        *(f32x4*)&Bt[rr][c32 + c * 4] = *(const f32x4*)&Wv[(size_t)(kt + rr) * HD + j0 + c32 + c * 4];
    }
    __syncthreads();
    #pragma unroll 8
    for (int k2 = 0; k2 < 64; ++k2) {
      float a[8];
      #pragma unroll
      for (int u = 0; u < 8; ++u) a[u] = At[ti * 8 + u][k2];
      f32x4 b = *(const f32x4*)&Bt[k2][tj * 4];
      float svk = svr[kt + k2], rvk = rvr[kt + k2];
      swa += b * svk; sca += b * rvk;
      #pragma unroll
      for (int u = 0; u < 8; ++u)
        #pragma unroll
        for (int v = 0; v < 4; ++v) acc[u][v] += a[u] * b[v];
    }
  }
  int j = j0 + tj * 4;
  f32x4 bv4 = *(const f32x4*)&bv[j];
  f32x4 wnb;
  #pragma unroll
  for (int v = 0; v < 4; ++v) wnb[v] = swa[v] + 20000.0f * bv4[v];
  if (blockIdx.x == 0 && ti == 0) {
    float ac = scal[5], dc = scal[4];
    f32x4 ccv;
    #pragma unroll
    for (int v = 0; v < 4; ++v) ccv[v] = sca[v] + ac * bv4[v] + dc * wnb[v];
    *(f32x4*)&cc[j] = ccv;
  }
  #pragma unroll
  for (int u = 0; u < 8; ++u) {
    int i = i0 + ti * 8 + u;
    float tci = tc[i], uci = uc[i];
    f32x4 o;
    #pragma unroll
    for (int v = 0; v < 4; ++v)
      o[v] = acc[u][v] + tci * bv4[v] + uci * wnb[v];
    *(f32x4*)&Gc[(size_t)i * HD + j] = o;
  }
}

// merged: [0,17) scal2 | [17,81) M = Gc Gc^T 64x64 tiles | [81,225) Hc partials
__global__ __launch_bounds__(256) void k_post(
    const float* __restrict__ Gc, const float* __restrict__ cc,
    const float* __restrict__ Wo, const float* __restrict__ g,
    const float* __restrict__ lnb, const float* __restrict__ scal_c,
    unsigned short* __restrict__ Bt2, float* __restrict__ M_part,
    float* __restrict__ Hc_part, float* __restrict__ scal) {
  __shared__ float SMEM[8768];
  int b = blockIdx.x, t = threadIdx.x;
  if (b < 17) {
    int lane = t & 63, w = t >> 6;
    if (b < 16) {
      int rb = b * 16 + w * 4;
      for (int q2 = 0; q2 < 4; ++q2) {
        int row = rb + q2;
        float s1 = 0.f, s2 = 0.f;
        #pragma unroll
        for (int c = 0; c < 8; ++c) {
          int kk2 = c * 256 + lane * 4;
          f32x4 g4 = *(const f32x4*)&Gc[(size_t)row * HD + kk2];
          f32x4 c4v = *(const f32x4*)&cc[kk2];
          #pragma unroll
          for (int u = 0; u < 4; ++u) { s1 += g4[u]; s2 += g4[u] * c4v[u]; }
        }
        WRED(s1); WRED(s2);
        if (lane == 0) {
          int base = ((256 + (row >> 5)) * 64 + ((row >> 3) & 3) * 16) * 8 + (row & 7);
          Bt2[base] = fbits(s1 * (1.0f / 2048.0f));
          Bt2[base + 8] = fbits(s2);
        }
      }
    } else {
      float s1 = 0.f, s2 = 0.f;
      #pragma unroll
      for (int c = 0; c < 2; ++c) {
        f32x4 v = *(const f32x4*)&cc[t * 8 + c * 4];
        #pragma unroll
        for (int u = 0; u < 4; ++u) { s1 += v[u]; s2 += v[u] * v[u]; }
      }
      WRED(s1); WRED(s2);
      if ((t & 63) == 0) { SMEM[t >> 6] = s1; SMEM[4 + (t >> 6)] = s2; }
      __syncthreads();
      if (t == 0) {
        scal[6] = SMEM[4] + SMEM[5] + SMEM[6] + SMEM[7];
        scal[7] = (SMEM[0] + SMEM[1] + SMEM[2] + SMEM[3]) * (1.0f / 2048.0f);
      }
      for (int idx = t; idx < 14 * 256; idx += 256) {
        int ci = idx >> 8, kk2 = idx & 255;
        int col = 514 + ci;
        Bt2[((256 + (kk2 >> 5)) * 64 + ((kk2 >> 3) & 3) * 16 + (col & 15)) * 8 + (kk2 & 7)] = 0;
      }
    }
  } else if (b < 81) {
    float (*Gi)[68] = (float(*)[68])SMEM;
    float (*Gj)[69] = (float(*)[69])(SMEM + 64 * 68);
    int idx = b - 17;
    int bx = idx & 3, by = (idx >> 2) & 3, z = idx >> 4;
    int i0 = bx * 64, j0 = by * 64;
    int ti = t >> 5, tj = t & 31;
    float acc[8][2] = {};
    for (int kt = 0; kt < 512; kt += 64) {
      int kb = z * 512 + kt;
      __syncthreads();
      {
        int rr = t >> 2, c16 = (t & 3) * 16;
        #pragma unroll
        for (int c = 0; c < 4; ++c) {
          *(f32x4*)&Gi[rr][c16 + c * 4] = *(const f32x4*)&Gc[(size_t)(i0 + rr) * HD + kb + c16 + c * 4];
          *(f32x4*)&Gj[rr][c16 + c * 4] = *(const f32x4*)&Gc[(size_t)(j0 + rr) * HD + kb + c16 + c * 4];
        }
      }
      __syncthreads();
      #pragma unroll 8
      for (int k2 = 0; k2 < 64; ++k2) {
        float a[8];
        #pragma unroll
        for (int u = 0; u < 8; ++u) a[u] = Gi[ti * 8 + u][k2];
        float b0 = Gj[tj * 2][k2], b1 = Gj[tj * 2 + 1][k2];
        #pragma unroll
        for (int u = 0; u < 8; ++u) { acc[u][0] += a[u] * b0; acc[u][1] += a[u] * b1; }
      }
    }
    #pragma unroll
    for (int u = 0; u < 8; ++u) {
      M_part[(size_t)z * 65536 + (i0 + ti * 8 + u) * 256 + j0 + tj * 2] = acc[u][0];
      M_part[(size_t)z * 65536 + (i0 + ti * 8 + u) * 256 + j0 + tj * 2 + 1] = acc[u][1];
    }
  } else {
    float (*At)[68] = (float(*)[68])SMEM;
    float (*Bt)[68] = (float(*)[68])(SMEM + 32 * 68);
    int idx = b - 81;
    int bx = idx % 9, rem = idx / 9, by = rem & 3, z = rem >> 2;
    int i0 = bx * 32, j0 = by * 64;
    float s2 = scal_c[2];
    int ti = t >> 5, tj = t & 31;
    float acc[4][2] = {};
    for (int kt = 0; kt < 512; kt += 64) {
      int kb = z * 512 + kt;
      __syncthreads();
      {
        int rr = t >> 3, c8 = (t & 7) * 8, gi = i0 + rr;
        #pragma unroll
        for (int h = 0; h < 8; h += 4) {
          f32x4 g4 = *(const f32x4*)&g[kb + c8 + h];
          f32x4 a;
          if (gi < 256) {
            f32x4 gg = *(const f32x4*)&Gc[(size_t)gi * HD + kb + c8 + h];
            #pragma unroll
            for (int u = 0; u < 4; ++u) a[u] = gg[u] * g4[u];
          } else if (gi == 256) {
            a = g4;
          } else if (gi == 257) {
            f32x4 c4v = *(const f32x4*)&cc[kb + c8 + h];
            #pragma unroll
            for (int u = 0; u < 4; ++u) a[u] = c4v[u] * g4[u];
          } else if (gi == 258) {
            a = *(const f32x4*)&lnb[kb + c8 + h];
          } else {
            a = (f32x4){0.f, 0.f, 0.f, 0.f};
          }
          *(f32x4*)&At[rr][c8 + h] = a;
        }
      }
      {
        int rr = t >> 2, c16 = (t & 3) * 16;
        #pragma unroll
        for (int c = 0; c < 4; ++c) {
          f32x4 bb = *(const f32x4*)&Wo[(size_t)(kb + rr) * 256 + j0 + c16 + c * 4];
          #pragma unroll
          for (int u = 0; u < 4; ++u) bb[u] *= s2;
          *(f32x4*)&Bt[rr][c16 + c * 4] = bb;
        }
      }
      __syncthreads();
      #pragma unroll 8
      for (int k2 = 0; k2 < 64; ++k2) {
        float a[4];
        #pragma unroll
        for (int u = 0; u < 4; ++u) a[u] = At[ti * 4 + u][k2];
        f32x2 b2 = *(const f32x2*)&Bt[k2][tj * 2];
        #pragma unroll
        for (int u = 0; u < 4; ++u) { acc[u][0] += a[u] * b2[0]; acc[u][1] += a[u] * b2[1]; }
      }
    }
    #pragma unroll
    for (int u = 0; u < 4; ++u) {
      Hc_part[(size_t)z * 73728 + (i0 + ti * 4 + u) * 256 + j0 + tj * 2] = acc[u][0];
      Hc_part[(size_t)z * 73728 + (i0 + ti * 4 + u) * 256 + j0 + tj * 2 + 1] = acc[u][1];
    }
  }
}

// reduce M/Hc partials -> Bt2 (wave-contiguous bf16); vectors wbar/hc/bc
__global__ __launch_bounds__(256) void k_red2(
    const float* __restrict__ M_part, const float* __restrict__ Hc_part,
    const float* __restrict__ bo, unsigned short* __restrict__ Bt2,
    float* __restrict__ wbar, float* __restrict__ hcv, float* __restrict__ bcv) {
  int bi = blockIdx.x, z2 = blockIdx.y, t = threadIdx.x;
  if (z2 == 2) {
    if (bi != 0) return;
    float s0 = 0.f, s1 = 0.f, s2 = 0.f;
    #pragma unroll
    for (int z = 0; z < 4; ++z) {
      s0 += Hc_part[(size_t)z * 73728 + 256 * 256 + t];
      s1 += Hc_part[(size_t)z * 73728 + 257 * 256 + t];
      s2 += Hc_part[(size_t)z * 73728 + 258 * 256 + t];
    }
    wbar[t] = s0; hcv[t] = s1; bcv[t] = s2 + bo[t];
    return;
  }
  __shared__ unsigned short T[64][256];
  const float* src = z2 ? Hc_part : M_part;
  const size_t sp = z2 ? 73728 : 65536;
  const int base = z2 ? 256 : 0;
  for (int ii = 0; ii < 64; ++ii) {
    int i = bi * 64 + ii;
    float s = 0.f;
    #pragma unroll
    for (int z = 0; z < 4; ++z) s += src[z * sp + i * 256 + t];
    T[ii][t] = fbits(s);
  }
  __syncthreads();
  const int col = base + t;
  #pragma unroll
  for (int c = 0; c < 64; c += 8) {
    u16x8 o;
    #pragma unroll
    for (int u = 0; u < 8; ++u) o[u] = T[c + u][t];
    int kk0 = bi * 64 + c;
    int addr = (((col >> 4) * 8 + (kk0 >> 5)) * 64 + ((kk0 >> 3) & 3) * 16 + (col & 15)) * 8;
    *(u16x8*)&Bt2[addr] = o;
  }
}

// fused final (512 thr, 8 waves, 64 cols/wave): y|z|mu|m2 = q @ Bt2 + LN epilogue
__global__ __launch_bounds__(512) void k_out(
    const float* __restrict__ q, const unsigned short* __restrict__ Bt2,
    const float* __restrict__ hcv, const float* __restrict__ wbar,
    const float* __restrict__ bcv, const float* __restrict__ scal,
    float* __restrict__ out) {
  __shared__ unsigned short As[32 * 264];
  __shared__ unsigned short zbuf[32][264];
  __shared__ float sqp[4][32];
  __shared__ float muL[32], m2L[32];
  const int t = threadIdx.x, lane = t & 63, wave = t >> 6;
  const int row0 = blockIdx.x * 32;
  const int r15 = lane & 15, kg = lane >> 4;
  {
    #pragma unroll
    for (int i = 0; i < 4; ++i) {
      int ch = i * 512 + t;
      int row = ch >> 6, c4 = (ch & 63) * 4;
      f32x4 v = *(const f32x4*)&q[(size_t)(row0 + row) * HIW + c4];
      bf16x4v o;
      #pragma unroll
      for (int u = 0; u < 4; ++u) o[u] = (__bf16)v[u];
      *(bf16x4v*)&As[row * 264 + c4] = o;
    }
  }
  __syncthreads();
  const bool isM = wave < 4;
  const int wcol = isM ? wave * 64 : 256 + (wave - 4) * 64;
  const int grp0 = wcol >> 4;
  f32x4 acc[2][5];
  #pragma unroll
  for (int m = 0; m < 2; ++m)
    #pragma unroll
    for (int n = 0; n < 5; ++n) acc[m][n] = (f32x4){0.f, 0.f, 0.f, 0.f};
  __builtin_amdgcn_s_setprio(1);
  #pragma unroll
  for (int ko = 0; ko < 8; ++ko) {
    bf16x8 af0 = *(const bf16x8*)&As[r15 * 264 + ko * 32 + kg * 8];
    bf16x8 af1 = *(const bf16x8*)&As[(16 + r15) * 264 + ko * 32 + kg * 8];
    #pragma unroll
    for (int ni = 0; ni < 5; ++ni) {
      if (ni == 4 && wave != 7) continue;
      const int grp = (ni == 4) ? 32 : grp0 + ni;
      bf16x8 bfr = *(const bf16x8*)&Bt2[(size_t)(grp * 8 + ko) * 512 + lane * 8];
      acc[0][ni] = __builtin_amdgcn_mfma_f32_16x16x32_bf16(af0, bfr, acc[0][ni], 0, 0, 0);
      acc[1][ni] = __builtin_amdgcn_mfma_f32_16x16x32_bf16(af1, bfr, acc[1][ni], 0, 0, 0);
    }
  }
  __builtin_amdgcn_s_setprio(0);
  if (isM) {
    #pragma unroll
    for (int m = 0; m < 2; ++m)
      #pragma unroll
      for (int r = 0; r < 4; ++r) {
        int rowl = m * 16 + kg * 4 + r;
        float p = 0.f;
        #pragma unroll
        for (int ni = 0; ni < 4; ++ni) {
          int col = wcol + ni * 16 + r15;
          p += acc[m][ni][r] * bf2f(As[rowl * 264 + col]);
        }
        p += __shfl_xor(p, 1); p += __shfl_xor(p, 2);
        p += __shfl_xor(p, 4); p += __shfl_xor(p, 8);
        if (r15 == 0) sqp[wave][rowl] = p;
      }
  } else {
    #pragma unroll
    for (int m = 0; m < 2; ++m)
      #pragma unroll
      for (int r = 0; r < 4; ++r) {
        int rowl = m * 16 + kg * 4 + r;
        #pragma unroll
        for (int ni = 0; ni < 4; ++ni)
          zbuf[rowl][(wcol - 256) + ni * 16 + r15] = fbits(acc[m][ni][r]);
      }
    if (wave == 7) {
      #pragma unroll
      for (int m = 0; m < 2; ++m)
        #pragma unroll
        for (int r = 0; r < 4; ++r) {
          int rowl = m * 16 + kg * 4 + r;
          if (r15 == 0) muL[rowl] = acc[m][4][r];
          if (r15 == 1) m2L[rowl] = acc[m][4][r];
        }
    }
  }
  __syncthreads();
  const float css = scal[6], cbar = scal[7];
  #pragma unroll
  for (int i = 0; i < 4; ++i) {
    const int row = i * 8 + wave;
    const int c4 = lane * 4;
    float mu = muL[row] + cbar;
    float ss = (sqp[0][row] + sqp[1][row]) + (sqp[2][row] + sqp[3][row]) +
               2.0f * m2L[row] + css;
    float var = ss * (1.0f / 2048.0f) - mu * mu;
    float rstd = rsqrtf(var + 1e-5f);
    u16x4 zh = *(const u16x4*)&zbuf[row][c4];
    f32x4 h4 = *(const f32x4*)&hcv[c4];
    f32x4 w4 = *(const f32x4*)&wbar[c4];
    f32x4 b4 = *(const f32x4*)&bcv[c4];
    f32x4 o;
    #pragma unroll
    for (int u = 0; u < 4; ++u)
      o[u] = rstd * (bf2f(zh[u]) + h4[u] - mu * w4[u]) + b4[u];
    *(f32x4*)&out[(size_t)(row0 + row) * HIW + c4] = o;
  }
}

extern "C" void kernel_launch(void* const* d_in, const int* in_sizes, int n_in,
                              void* d_out, int out_size, void* d_ws, size_t ws_size,
                              hipStream_t stream) {
  const float* q   = (const float*)d_in[0];
  const float* k   = (const float*)d_in[1];
  const float* v   = (const float*)d_in[2];
  const int* layer = (const int*)d_in[3];
  const float* Wq1 = (const float*)d_in[4];  const float* bq1 = (const float*)d_in[5];
  const float* Wk1 = (const float*)d_in[6];  const float* bk1 = (const float*)d_in[7];
  const float* Wq2 = (const float*)d_in[8];  const float* bq2 = (const float*)d_in[9];
  const float* Wk2 = (const float*)d_in[10]; const float* bk2 = (const float*)d_in[11];
  const float* Wv  = (const float*)d_in[12]; const float* bv  = (const float*)d_in[13];
  const float* lng = (const float*)d_in[14]; const float* lnb = (const float*)d_in[15];
  const float* Wo  = (const float*)d_in[16]; const float* bo  = (const float*)d_in[17];
  const float* lq1 = (const float*)d_in[18]; const float* lk1 = (const float*)d_in[19];
  const float* lq2 = (const float*)d_in[20]; const float* lk2 = (const float*)d_in[21];

  char* p = (char*)d_ws;
  unsigned short* kT = (unsigned short*)p;
  float* M_part  = (float*)p;
  float* Hc_part = (float*)(p + 1048576);
  unsigned short* Bt2 = (unsigned short*)(p + 1048576 + 1179648);
  p += (size_t)256 * NTP * 2;
  unsigned short* vT = (unsigned short*)p;
  float* Gc = (float*)p;
  p += (size_t)256 * NTP * 2;
  float* skp = (float*)p;     p += (size_t)320 * 256 * 4;
  float* svp = (float*)p;     p += (size_t)320 * 256 * 4;
  unsigned short* Pc_part = (unsigned short*)p; p += (size_t)32 * 65536 * 2;
  float* S  = (float*)p;      p += 65536 * 4;
  float* Pc = (float*)p;      p += 65536 * 4;
  float* sk = (float*)p;      p += 1024;
  float* sv = (float*)p;      p += 1024;
  float* gc = (float*)p;      p += 1024;
  float* uc = (float*)p;      p += 1024;
  float* tc = (float*)p;      p += 1024;
  float* rv = (float*)p;      p += 1024;
  float* cc = (float*)p;      p += 2048 * 4;
  float* Ac = (float*)p;      p += 65536 * 4;
  float* wbar = (float*)p;    p += 1024;
  float* hcv  = (float*)p;    p += 1024;
  float* bcv  = (float*)p;    p += 1024;
  float* scal = (float*)p;    p += 256;

  const dim3 b256(256);
  k_front<<<dim3(770), b256, 0, stream>>>(k, v, Wq1, Wk1, Wq2, Wk2,
      lq1, lk1, lq2, lk2, bq1, bk1, bq2, bk2, layer, kT, vT, skp, svp, Pc_part, scal, S);
  k_mid<<<dim3(322), dim3(512), 0, stream>>>(kT, vT, S, Pc_part, skp, svp, Pc, sk, sv,
      Wk1, Wk2, Wq1, Wq2, bq1, bq2, bk1, bk2, scal, gc, uc);
  k_ac<<<dim3(34), b256, 0, stream>>>(Pc, S, gc, sk, Ac, tc, rv, scal);
  k_gc<<<dim3(4, 16), b256, 0, stream>>>(Ac, Wv, tc, uc, sv, rv, bv, scal, Gc, cc);
  k_post<<<dim3(225), b256, 0, stream>>>(Gc, cc, Wo, lng, lnb, scal, Bt2, M_part, Hc_part, scal);
  k_red2<<<dim3(4, 3), b256, 0, stream>>>(M_part, Hc_part, bo, Bt2, wbar, hcv, bcv);
  k_out<<<dim3(625), dim3(512), 0, stream>>>(q, Bt2, hcv, wbar, bcv, scal, (float*)d_out);
}